// Round 2
// baseline (924.600 us; speedup 1.0000x reference)
//
#include <hip/hip_runtime.h>

typedef unsigned short u16;
typedef unsigned int   u32;
typedef __bf16 bf16x8 __attribute__((ext_vector_type(8)));
typedef float  f32x4  __attribute__((ext_vector_type(4)));

#define EPS 1e-5f

__device__ __forceinline__ float b2f(u16 u){ union{u32 i; float f;} v; v.i=((u32)u)<<16; return v.f; }
__device__ __forceinline__ u16 f2b(float f){
  u32 x = __float_as_uint(f);
  u32 r = x + 0x7fffu + ((x>>16)&1u);   // round-to-nearest-even
  return (u16)(r>>16);
}

// ---------------- GEMM: C[M,128] = act(A[M,K] @ (Bhi+Blo) + bias) ----------------
// A fp32 (AF32) or bf16; B pre-split hi/lo bf16, pre-transposed [128,K] in global
// (tiny, L1/L2-resident). C bf16. Wave computes 16 rows x 128 cols via 16x16x32 MFMA.
template<int K, bool RELU, bool HASBIAS, bool AF32>
__global__ __launch_bounds__(256) void k_gemm(const void* __restrict__ Av,
                                              const u16* __restrict__ BhiT,
                                              const u16* __restrict__ BloT,
                                              const float* __restrict__ bias,
                                              u16* __restrict__ C, int M)
{
  const int tid = threadIdx.x;
  const int wid = tid >> 6, lane = tid & 63, q = lane >> 4, r16 = lane & 15;
  const int ntiles = M >> 6;            // M divisible by 64 (200000 = 3125*64)
  for (int tile = blockIdx.x; tile < ntiles; tile += gridDim.x) {
    const int arow = (tile << 6) + (wid << 4) + r16;
    bf16x8 av[K / 32];
    if (AF32) {
      const float* Af = (const float*)Av + (size_t)arow * K + q * 8;
#pragma unroll
      for (int kk = 0; kk < K / 32; kk++) {
        f32x4 x0 = *(const f32x4*)(Af + kk * 32);
        f32x4 x1 = *(const f32x4*)(Af + kk * 32 + 4);
#pragma unroll
        for (int j = 0; j < 4; j++) { av[kk][j] = (__bf16)x0[j]; av[kk][4 + j] = (__bf16)x1[j]; }
      }
    } else {
      const u16* Ab = (const u16*)Av + (size_t)arow * K + q * 8;
#pragma unroll
      for (int kk = 0; kk < K / 32; kk++) av[kk] = *(const bf16x8*)(Ab + kk * 32);
    }
    f32x4 acc[8];
#pragma unroll
    for (int nb = 0; nb < 8; nb++) acc[nb] = (f32x4){0.f, 0.f, 0.f, 0.f};
#pragma unroll
    for (int kk = 0; kk < K / 32; kk++) {
#pragma unroll
      for (int nb = 0; nb < 8; nb++) {
        const int bo = (nb * 16 + r16) * K + kk * 32 + q * 8;
        const bf16x8 bh = *(const bf16x8*)(BhiT + bo);
        const bf16x8 bl = *(const bf16x8*)(BloT + bo);
        acc[nb] = __builtin_amdgcn_mfma_f32_16x16x32_bf16(av[kk], bh, acc[nb], 0, 0, 0);
        acc[nb] = __builtin_amdgcn_mfma_f32_16x16x32_bf16(av[kk], bl, acc[nb], 0, 0, 0);
      }
    }
    const int rbase = (tile << 6) + (wid << 4) + (q << 2);
#pragma unroll
    for (int nb = 0; nb < 8; nb++) {
      const int col = nb * 16 + r16;
      const float bv = HASBIAS ? bias[col] : 0.f;
#pragma unroll
      for (int r = 0; r < 4; r++) {
        float v = acc[nb][r] + bv;
        if (RELU) v = fmaxf(v, 0.f);
        C[(size_t)(rbase + r) * 128 + col] = f2b(v);
      }
    }
  }
}

// ---------------- split fp32 W[K,128] -> hi/lo bf16 transposed [128,K] ----------------
__global__ void k_split(const float* __restrict__ W, u16* __restrict__ hiT,
                        u16* __restrict__ loT, int K)
{
  int i = blockIdx.x * 256 + threadIdx.x;
  if (i < K * 128) {
    int k = i >> 7, n = i & 127;
    float w = W[i];
    u16 h = f2b(w);
    hiT[n * K + k] = h;
    loT[n * K + k] = f2b(w - b2f(h));
  }
}

// ---------------- degree histogram ----------------
__global__ void k_deg(const int* __restrict__ dst, int* __restrict__ deg, int E)
{
  int e = blockIdx.x * 256 + threadIdx.x;
  if (e < E) atomicAdd(&deg[dst[e]], 1);
}

// ---------------- prefix scan of deg (3 kernels, 2048 elems/block) ----------------
__global__ void k_scan1(const int* __restrict__ deg, int* __restrict__ bsum, int n)
{
  __shared__ int s[256];
  const int t = threadIdx.x;
  const int base = blockIdx.x * 2048 + t * 8;
  int sum = 0;
#pragma unroll
  for (int j = 0; j < 8; j++) { int i = base + j; if (i < n) sum += deg[i]; }
  s[t] = sum; __syncthreads();
  for (int o = 128; o; o >>= 1) { if (t < o) s[t] += s[t + o]; __syncthreads(); }
  if (t == 0) bsum[blockIdx.x] = s[0];
}

__global__ void k_scan2(const int* __restrict__ bsum, int* __restrict__ bofs, int nb)
{
  __shared__ int s[256];
  const int t = threadIdx.x;
  int v = (t < nb) ? bsum[t] : 0;
  s[t] = v; __syncthreads();
  for (int o = 1; o < 256; o <<= 1) {
    int x = (t >= o) ? s[t - o] : 0;
    __syncthreads();
    s[t] += x;
    __syncthreads();
  }
  if (t < nb) bofs[t] = s[t] - v;   // exclusive
}

__global__ void k_scan3(const int* __restrict__ deg, const int* __restrict__ bofs,
                        int* __restrict__ offsets, int* __restrict__ cursor,
                        float* __restrict__ dinv, int n, int E)
{
  __shared__ int s[256];
  const int t = threadIdx.x;
  const int base = blockIdx.x * 2048 + t * 8;
  int loc[8]; int sum = 0;
#pragma unroll
  for (int j = 0; j < 8; j++) { int i = base + j; int d = (i < n) ? deg[i] : 0; loc[j] = sum; sum += d; }
  const int own = sum;
  s[t] = sum; __syncthreads();
  for (int o = 1; o < 256; o <<= 1) {
    int x = (t >= o) ? s[t - o] : 0;
    __syncthreads();
    s[t] += x;
    __syncthreads();
  }
  const int tbase = bofs[blockIdx.x] + s[t] - own;
#pragma unroll
  for (int j = 0; j < 8; j++) {
    int i = base + j;
    if (i < n) {
      int off = tbase + loc[j];
      offsets[i] = off; cursor[i] = off;
      dinv[i] = rsqrtf((float)(deg[i] + 1));   // +1 self-loop
      if (i == n - 1) offsets[n] = E;
    }
  }
}

__global__ void k_scatter(const int* __restrict__ src, const int* __restrict__ dst,
                          int* __restrict__ cursor, int* __restrict__ elist, int E)
{
  int e = blockIdx.x * 256 + threadIdx.x;
  if (e < E) { int d = dst[e]; int p = atomicAdd(&cursor[d], 1); elist[p] = src[e]; }
}

// ---------------- GCN aggregation: one wave per node, 2 feats/lane ----------------
__global__ __launch_bounds__(256) void k_agg(const u16* __restrict__ xw, const int* __restrict__ offsets,
                                             const int* __restrict__ elist, const float* __restrict__ dinv,
                                             const float* __restrict__ bg, u16* __restrict__ h0, int n)
{
  const int lane = threadIdx.x & 63;
  const int wid  = (blockIdx.x * 256 + threadIdx.x) >> 6;
  const int nw   = gridDim.x * 4;
  const float bv0 = bg[2 * lane], bv1 = bg[2 * lane + 1];
  for (int node = wid; node < n; node += nw) {
    const int s0 = offsets[node], s1 = offsets[node + 1];
    const float di = dinv[node];
    float a0 = 0.f, a1 = 0.f;
    for (int p = s0; p < s1; p++) {
      const int sidx = elist[p];
      const float w = dinv[sidx];
      const u32 v = *(const u32*)(xw + (size_t)sidx * 128 + 2 * lane);
      a0 += b2f((u16)v) * w; a1 += b2f((u16)(v >> 16)) * w;
    }
    { const u32 v = *(const u32*)(xw + (size_t)node * 128 + 2 * lane);
      a0 += b2f((u16)v) * di; a1 += b2f((u16)(v >> 16)) * di; }
    a0 = fmaxf(a0 * di + bv0, 0.f);
    a1 = fmaxf(a1 * di + bv1, 0.f);
    *(u32*)(h0 + (size_t)node * 128 + 2 * lane) = (u32)f2b(a0) | ((u32)f2b(a1) << 16);
  }
}

// ---------------- BN stats: per-feature sum & sumsq over N rows ----------------
__global__ __launch_bounds__(256) void k_stats(const u16* __restrict__ h, float* __restrict__ stats, int n)
{
  const int t = threadIdx.x, f = t & 127, half = t >> 7;
  float s = 0.f, q = 0.f;
  for (int r = blockIdx.x * 2 + half; r < n; r += gridDim.x * 2) {
    float v = b2f(h[(size_t)r * 128 + f]);
    s += v; q += v * v;
  }
  __shared__ float red[512];
  red[t] = s; red[256 + t] = q; __syncthreads();
  if (t < 128) {
    atomicAdd(&stats[f],       red[t] + red[t + 128]);
    atomicAdd(&stats[128 + f], red[256 + t] + red[256 + t + 128]);
  }
}

__global__ void k_cnt(const int* __restrict__ batch, int* __restrict__ cnt, int n)
{
  int i = blockIdx.x * 256 + threadIdx.x;
  if (i < n) atomicAdd(&cnt[batch[i]], 1);
}

// ---- fold BN0 into W1: W1p = diag(a0) W1 (hi/lo bf16, transposed), b1p = c0@W1 + b1 ----
__global__ void k_prep1(const float* __restrict__ stats0, const float* __restrict__ W1,
                        const float* __restrict__ b1, const float* __restrict__ g0,
                        const float* __restrict__ be0, u16* __restrict__ W1hiT,
                        u16* __restrict__ W1loT, float* __restrict__ b1p, float n)
{
  __shared__ float A[128], Csh[128];
  const int t = threadIdx.x;  // 128 threads
  const float mu = stats0[t] / n;
  const float var = fmaxf(stats0[128 + t] / n - mu * mu, 0.f);
  const float a = g0[t] * rsqrtf(var + EPS);
  A[t] = a; Csh[t] = be0[t] - mu * a;
  __syncthreads();
  float acc = b1[t];
  for (int k = 0; k < 128; k++) {
    const float w0 = W1[k * 128 + t];
    acc += Csh[k] * w0;
    const float w = A[k] * w0;
    const u16 h = f2b(w);
    W1hiT[t * 128 + k] = h;
    W1loT[t * 128 + k] = f2b(w - b2f(h));
  }
  b1p[t] = acc;
}

// ---------------- fold BN1/BN2 + concat + W3 into w1f,w2f,constS ----------------
__global__ void k_prep2(const float* __restrict__ stats1, const float* __restrict__ stats2,
                        const float* __restrict__ g1, const float* __restrict__ be1,
                        const float* __restrict__ g2, const float* __restrict__ be2,
                        const float* __restrict__ W3, const float* __restrict__ b3,
                        float* __restrict__ w1f, float* __restrict__ w2f,
                        float* __restrict__ constS, float n)
{
  __shared__ float red[256];
  const int t = threadIdx.x;  // 256 threads
  float c, wv;
  if (t < 128) {
    const float mu = stats1[t] / n;
    const float var = fmaxf(stats1[128 + t] / n - mu * mu, 0.f);
    const float a = g1[t] * rsqrtf(var + EPS);
    c = be1[t] - mu * a;
    wv = W3[t];
    w1f[t] = a * wv;
  } else {
    const int f = t - 128;
    const float mu = stats2[f] / n;
    const float var = fmaxf(stats2[128 + f] / n - mu * mu, 0.f);
    const float a = g2[f] * rsqrtf(var + EPS);
    c = be2[f] - mu * a;
    wv = W3[t];
    w2f[f] = a * wv;
  }
  red[t] = c * wv; __syncthreads();
  for (int o = 128; o; o >>= 1) { if (t < o) red[t] += red[t + o]; __syncthreads(); }
  if (t == 0) { constS[0] = red[0] + b3[0]; constS[1] = b3[0]; }
}

// ---------------- pooled dot: s[n]=h1[n].w1f+h2[n].w2f, segment-sum into dots[b] ----------------
__global__ __launch_bounds__(256) void k_pool(const u16* __restrict__ h1, const u16* __restrict__ h2,
                                              const int* __restrict__ batch, const float* __restrict__ w1f,
                                              const float* __restrict__ w2f, float* __restrict__ dots, int n)
{
  const int t = threadIdx.x;
  const u16* h = (t < 128) ? h1 : h2;
  const int f = t & 127;
  const float wf = (t < 128) ? w1f[f] : w2f[f];
  const int chunk = (n + gridDim.x - 1) / gridDim.x;
  const int start = blockIdx.x * chunk;
  const int end = (start + chunk < n) ? (start + chunk) : n;
  if (start >= end) return;
  __shared__ float red[256];
  int cur = batch[start];
  float acc = 0.f;
  for (int node = start; node < end; node++) {
    const int b = batch[node];
    if (b != cur) {
      red[t] = acc; __syncthreads();
      for (int o = 128; o; o >>= 1) { if (t < o) red[t] += red[t + o]; __syncthreads(); }
      if (t == 0) atomicAdd(&dots[cur], red[0]);
      __syncthreads();
      acc = 0.f; cur = b;
    }
    acc += b2f(h[(size_t)node * 128 + f]) * wf;
  }
  red[t] = acc; __syncthreads();
  for (int o = 128; o; o >>= 1) { if (t < o) red[t] += red[t + o]; __syncthreads(); }
  if (t == 0) atomicAdd(&dots[cur], red[0]);
}

__global__ void k_out(const float* __restrict__ dots, const int* __restrict__ cnt,
                      const float* __restrict__ constS, float* __restrict__ out, int B)
{
  int b = blockIdx.x * 256 + threadIdx.x;
  if (b < B) {
    out[b] = (cnt[b] > 0) ? (dots[b] / (float)cnt[b] + constS[0]) : constS[1];
  }
}

extern "C" void kernel_launch(void* const* d_in, const int* in_sizes, int n_in,
                              void* d_out, int out_size, void* d_ws, size_t ws_size,
                              hipStream_t stream)
{
  const float* x    = (const float*)d_in[0];
  const float* act  = (const float*)d_in[1];
  const float* Wg   = (const float*)d_in[2];
  const float* bg   = (const float*)d_in[3];
  const float* g0   = (const float*)d_in[4];
  const float* be0  = (const float*)d_in[5];
  const float* W1   = (const float*)d_in[6];
  const float* b1   = (const float*)d_in[7];
  const float* g1   = (const float*)d_in[8];
  const float* be1  = (const float*)d_in[9];
  const float* W2   = (const float*)d_in[10];
  const float* b2   = (const float*)d_in[11];
  const float* g2   = (const float*)d_in[12];
  const float* be2  = (const float*)d_in[13];
  const float* W3   = (const float*)d_in[14];
  const float* b3   = (const float*)d_in[15];
  const int* eidx   = (const int*)d_in[16];
  const int* batch  = (const int*)d_in[17];

  const int N = in_sizes[17];          // 200000
  const int E = in_sizes[16] / 2;      // 1600000
  const int B = out_size;              // 1000
  const int* src = eidx;
  const int* dst = eidx + E;

  char* ws = (char*)d_ws;
  size_t off = 0;
  auto alloc = [&](size_t bytes) -> char* {
    off = (off + 255) & ~(size_t)255;
    char* p = ws + off; off += bytes; return p;
  };

  u16* xw = (u16*)alloc((size_t)N * 128 * 2);   // xw, later reused as h1
  u16* h0 = (u16*)alloc((size_t)N * 128 * 2);
  u16* h2 = (u16*)alloc((size_t)N * 128 * 2);

  const size_t zbytes = (size_t)N * 4 + 3 * 256 * 4 + (size_t)B * 4 + (size_t)B * 4;
  char* zbase   = alloc(zbytes);
  int*   deg    = (int*)zbase;
  float* stats0 = (float*)(zbase + (size_t)N * 4);
  float* stats1 = stats0 + 256;
  float* stats2 = stats1 + 256;
  float* dots   = (float*)(stats2 + 256);
  int*   cnt    = (int*)(dots + B);

  int*   offsets = (int*)alloc((size_t)(N + 1) * 4);
  int*   cursor  = (int*)alloc((size_t)N * 4);
  float* dinv    = (float*)alloc((size_t)N * 4);
  int*   elist   = (int*)alloc((size_t)E * 4);
  int*   bsum    = (int*)alloc(256 * 4);
  int*   bofs    = (int*)alloc(256 * 4);
  u16*   WghiT   = (u16*)alloc(128 * 64 * 2);
  u16*   WgloT   = (u16*)alloc(128 * 64 * 2);
  u16*   W1hiT   = (u16*)alloc(128 * 128 * 2);
  u16*   W1loT   = (u16*)alloc(128 * 128 * 2);
  u16*   W2hiT   = (u16*)alloc(128 * 32 * 2);
  u16*   W2loT   = (u16*)alloc(128 * 32 * 2);
  float* b1p     = (float*)alloc(128 * 4);
  float* w1f     = (float*)alloc(128 * 4);
  float* w2f     = (float*)alloc(128 * 4);
  float* constS  = (float*)alloc(2 * 4);

  hipMemsetAsync(zbase, 0, zbytes, stream);

  const int nscan = (N + 2047) / 2048;

  // weight splits
  k_split<<<(64 * 128 + 255) / 256, 256, 0, stream>>>(Wg, WghiT, WgloT, 64);
  k_split<<<(32 * 128 + 255) / 256, 256, 0, stream>>>(W2, W2hiT, W2loT, 32);
  // xw = x @ W_gcn  (fp32 A, bf16 out)
  k_gemm<64, false, false, true><<<1024, 256, 0, stream>>>(x, WghiT, WgloT, nullptr, xw, N);
  // CSR build
  k_deg<<<(E + 255) / 256, 256, 0, stream>>>(dst, deg, E);
  k_scan1<<<nscan, 256, 0, stream>>>(deg, bsum, N);
  k_scan2<<<1, 256, 0, stream>>>(bsum, bofs, nscan);
  k_scan3<<<nscan, 256, 0, stream>>>(deg, bofs, offsets, cursor, dinv, N, E);
  k_scatter<<<(E + 255) / 256, 256, 0, stream>>>(src, dst, cursor, elist, E);
  // h0 = relu(GCN agg + b_gcn)
  k_agg<<<2048, 256, 0, stream>>>(xw, offsets, elist, dinv, bg, h0, N);
  k_stats<<<1024, 256, 0, stream>>>(h0, stats0, N);
  k_cnt<<<(N + 255) / 256, 256, 0, stream>>>(batch, cnt, N);
  // fold BN0 into W1
  k_prep1<<<1, 128, 0, stream>>>(stats0, W1, b1, g0, be0, W1hiT, W1loT, b1p, (float)N);
  // h1 = relu(h0n @ W1 + b1)  (into xw buffer)
  k_gemm<128, true, true, false><<<1024, 256, 0, stream>>>(h0, W1hiT, W1loT, b1p, xw, N);
  k_stats<<<1024, 256, 0, stream>>>(xw, stats1, N);
  // h2 = relu(action @ W2 + b2)  (fp32 A)
  k_gemm<32, true, true, true><<<1024, 256, 0, stream>>>(act, W2hiT, W2loT, b2, h2, N);
  k_stats<<<1024, 256, 0, stream>>>(h2, stats2, N);
  // fold BN1/BN2 + W3
  k_prep2<<<1, 256, 0, stream>>>(stats1, stats2, g1, be1, g2, be2, W3, b3, w1f, w2f, constS, (float)N);
  // segment pooled dot + output
  k_pool<<<1024, 256, 0, stream>>>(xw, h2, batch, w1f, w2f, dots, N);
  k_out<<<(B + 255) / 256, 256, 0, stream>>>(dots, cnt, constS, (float*)d_out, B);
}

// Round 3
// 815.139 us; speedup vs baseline: 1.1343x; 1.1343x over previous
//
#include <hip/hip_runtime.h>

typedef unsigned short u16;
typedef unsigned int   u32;
typedef __bf16 bf16x8 __attribute__((ext_vector_type(8)));
typedef float  f32x4  __attribute__((ext_vector_type(4)));

#define EPS 1e-5f

__device__ __forceinline__ float b2f(u16 u){ union{u32 i; float f;} v; v.i=((u32)u)<<16; return v.f; }
__device__ __forceinline__ u16 f2b(float f){
  u32 x = __float_as_uint(f);
  u32 r = x + 0x7fffu + ((x>>16)&1u);   // round-to-nearest-even
  return (u16)(r>>16);
}

// ---------------- GEMM: C[M,128] = act(A[M,K] @ (Bhi+Blo) + bias) ----------------
// B pre-split hi/lo bf16, pre-transposed [128,K] in global; staged ONCE into LDS
// with XOR swizzle (no pad -> K=128 fits 64KB exactly; swizzle kills bank conflicts).
// Wave computes 16 rows x 128 cols via 16x16x32 MFMA, hi+lo for fp32-grade weights.
template<int K, bool RELU, bool HASBIAS, bool AF32>
__global__ __launch_bounds__(256) void k_gemm(const void* __restrict__ Av,
                                              const u16* __restrict__ BhiT,
                                              const u16* __restrict__ BloT,
                                              const float* __restrict__ bias,
                                              u16* __restrict__ C, int M)
{
  constexpr int KM = K / 8;                 // 8-elem blocks per row
  __shared__ u16 lds[2 * 128 * K];          // [hi|lo][128 cols][K swizzled]
  const int tid = threadIdx.x;
  for (int i = tid; i < 128 * KM; i += 256) {
    const int n = i / KM, kb = i % KM;
    const int kb2 = kb ^ (n & (KM - 1));
    *(uint4*)(&lds[(n * KM + kb2) * 8])           = *(const uint4*)(BhiT + i * 8);
    *(uint4*)(&lds[128 * K + (n * KM + kb2) * 8]) = *(const uint4*)(BloT + i * 8);
  }
  __syncthreads();
  const int wid = tid >> 6, lane = tid & 63, q = lane >> 4, r16 = lane & 15;
  const int ntiles = M >> 6;                // M divisible by 64 (200000 = 3125*64)
  for (int tile = blockIdx.x; tile < ntiles; tile += gridDim.x) {
    const int arow = (tile << 6) + (wid << 4) + r16;
    bf16x8 av[K / 32];
    if (AF32) {
      const float* Af = (const float*)Av + (size_t)arow * K + q * 8;
#pragma unroll
      for (int kk = 0; kk < K / 32; kk++) {
        f32x4 x0 = *(const f32x4*)(Af + kk * 32);
        f32x4 x1 = *(const f32x4*)(Af + kk * 32 + 4);
#pragma unroll
        for (int j = 0; j < 4; j++) { av[kk][j] = (__bf16)x0[j]; av[kk][4 + j] = (__bf16)x1[j]; }
      }
    } else {
      const u16* Ab = (const u16*)Av + (size_t)arow * K + q * 8;
#pragma unroll
      for (int kk = 0; kk < K / 32; kk++) av[kk] = *(const bf16x8*)(Ab + kk * 32);
    }
    f32x4 acc[8];
#pragma unroll
    for (int nb = 0; nb < 8; nb++) acc[nb] = (f32x4){0.f, 0.f, 0.f, 0.f};
#pragma unroll
    for (int kk = 0; kk < K / 32; kk++) {
#pragma unroll
      for (int nb = 0; nb < 8; nb++) {
        const int n = nb * 16 + r16;
        const int kb2 = (kk * 4 + q) ^ (n & (KM - 1));
        const bf16x8 bh = *(const bf16x8*)(&lds[(n * KM + kb2) * 8]);
        const bf16x8 bl = *(const bf16x8*)(&lds[128 * K + (n * KM + kb2) * 8]);
        acc[nb] = __builtin_amdgcn_mfma_f32_16x16x32_bf16(av[kk], bh, acc[nb], 0, 0, 0);
        acc[nb] = __builtin_amdgcn_mfma_f32_16x16x32_bf16(av[kk], bl, acc[nb], 0, 0, 0);
      }
    }
    const int rbase = (tile << 6) + (wid << 4) + (q << 2);
#pragma unroll
    for (int nb = 0; nb < 8; nb++) {
      const int col = nb * 16 + r16;
      const float bv = HASBIAS ? bias[col] : 0.f;
#pragma unroll
      for (int r = 0; r < 4; r++) {
        float v = acc[nb][r] + bv;
        if (RELU) v = fmaxf(v, 0.f);
        C[(size_t)(rbase + r) * 128 + col] = f2b(v);
      }
    }
  }
}

// ---------------- split fp32 W[K,128] -> hi/lo bf16 transposed [128,K] ----------------
__global__ void k_split(const float* __restrict__ W, u16* __restrict__ hiT,
                        u16* __restrict__ loT, int K)
{
  int i = blockIdx.x * 256 + threadIdx.x;
  if (i < K * 128) {
    int k = i >> 7, n = i & 127;
    float w = W[i];
    u16 h = f2b(w);
    hiT[n * K + k] = h;
    loT[n * K + k] = f2b(w - b2f(h));
  }
}

// ---------------- cast x fp32 [N,64] -> bf16 ----------------
__global__ void k_cast(const float* __restrict__ x, u16* __restrict__ xb, int n)
{
  int i = (blockIdx.x * 256 + threadIdx.x) * 8;
  if (i < n) {
    f32x4 a = *(const f32x4*)(x + i);
    f32x4 b = *(const f32x4*)(x + i + 4);
    u16 o[8];
#pragma unroll
    for (int j = 0; j < 4; j++) { o[j] = f2b(a[j]); o[4 + j] = f2b(b[j]); }
    *(uint4*)(xb + i) = *(uint4*)o;
  }
}

// ---------------- degree histogram ----------------
__global__ void k_deg(const int* __restrict__ dst, int* __restrict__ deg, int E)
{
  int e = blockIdx.x * 256 + threadIdx.x;
  if (e < E) atomicAdd(&deg[dst[e]], 1);
}

// ------- prefix scan of (deg+1) incl. self-loops (3 kernels, 2048 elems/block) -------
__global__ void k_scan1(const int* __restrict__ deg, int* __restrict__ bsum, int n)
{
  __shared__ int s[256];
  const int t = threadIdx.x;
  const int base = blockIdx.x * 2048 + t * 8;
  int sum = 0;
#pragma unroll
  for (int j = 0; j < 8; j++) { int i = base + j; if (i < n) sum += deg[i] + 1; }
  s[t] = sum; __syncthreads();
  for (int o = 128; o; o >>= 1) { if (t < o) s[t] += s[t + o]; __syncthreads(); }
  if (t == 0) bsum[blockIdx.x] = s[0];
}

__global__ void k_scan2(const int* __restrict__ bsum, int* __restrict__ bofs, int nb)
{
  __shared__ int s[256];
  const int t = threadIdx.x;
  int v = (t < nb) ? bsum[t] : 0;
  s[t] = v; __syncthreads();
  for (int o = 1; o < 256; o <<= 1) {
    int x = (t >= o) ? s[t - o] : 0;
    __syncthreads();
    s[t] += x;
    __syncthreads();
  }
  if (t < nb) bofs[t] = s[t] - v;   // exclusive
}

// scan3 also seeds the self-loop edge (elist[off]=i) and sets cursor past it
__global__ void k_scan3(const int* __restrict__ deg, const int* __restrict__ bofs,
                        int* __restrict__ offsets, int* __restrict__ cursor,
                        float* __restrict__ dinv, int* __restrict__ elist, int n, int Etot)
{
  __shared__ int s[256];
  const int t = threadIdx.x;
  const int base = blockIdx.x * 2048 + t * 8;
  int loc[8]; int sum = 0;
#pragma unroll
  for (int j = 0; j < 8; j++) { int i = base + j; int d = (i < n) ? deg[i] + 1 : 0; loc[j] = sum; sum += d; }
  const int own = sum;
  s[t] = sum; __syncthreads();
  for (int o = 1; o < 256; o <<= 1) {
    int x = (t >= o) ? s[t - o] : 0;
    __syncthreads();
    s[t] += x;
    __syncthreads();
  }
  const int tbase = bofs[blockIdx.x] + s[t] - own;
#pragma unroll
  for (int j = 0; j < 8; j++) {
    int i = base + j;
    if (i < n) {
      int off = tbase + loc[j];
      offsets[i] = off;
      elist[off] = i;            // self-loop
      cursor[i] = off + 1;
      dinv[i] = rsqrtf((float)(deg[i] + 1));
      if (i == n - 1) offsets[n] = Etot;
    }
  }
}

__global__ void k_scatter(const int* __restrict__ src, const int* __restrict__ dst,
                          int* __restrict__ cursor, int* __restrict__ elist, int E)
{
  int e = blockIdx.x * 256 + threadIdx.x;
  if (e < E) { int d = dst[e]; int p = atomicAdd(&cursor[d], 1); elist[p] = src[e]; }
}

// ------- GCN aggregation on x (64 bf16 feats, 128B rows): agg commutes with W -------
// One wave per node; lanes 0-31 process even edge slots, lanes 32-63 odd; combine
// via shfl_xor(32). Self-loop is a regular CSR entry (weight dinv[self]=di, uniform).
__global__ __launch_bounds__(256) void k_agg(const u16* __restrict__ xb, const int* __restrict__ offsets,
                                             const int* __restrict__ elist, const float* __restrict__ dinv,
                                             u16* __restrict__ aggx, int n)
{
  const int lane = threadIdx.x & 63;
  const int half = lane >> 5, l32 = lane & 31;
  const int wid  = (blockIdx.x * 256 + threadIdx.x) >> 6;
  const int nw   = gridDim.x * 4;
  for (int node = wid; node < n; node += nw) {
    const int s0 = offsets[node], s1 = offsets[node + 1];
    const float di = dinv[node];
    float a0 = 0.f, a1 = 0.f;
    for (int p = s0; p < s1; p += 2) {
      const int pi = p + half;
      if (pi < s1) {
        const int sidx = elist[pi];
        const float w = dinv[sidx];
        const u32 v = *(const u32*)(xb + (size_t)sidx * 64 + 2 * l32);
        a0 += b2f((u16)v) * w; a1 += b2f((u16)(v >> 16)) * w;
      }
    }
    a0 += __shfl_xor(a0, 32, 64);
    a1 += __shfl_xor(a1, 32, 64);
    if (half == 0) {
      const u32 o = (u32)f2b(a0 * di) | ((u32)f2b(a1 * di) << 16);
      *(u32*)(aggx + (size_t)node * 64 + 2 * l32) = o;
    }
  }
}

// ---------------- BN stats: per-feature sum & sumsq over N rows ----------------
__global__ __launch_bounds__(256) void k_stats(const u16* __restrict__ h, float* __restrict__ stats, int n)
{
  const int t = threadIdx.x, f = t & 127, half = t >> 7;
  float s = 0.f, q = 0.f;
  for (int r = blockIdx.x * 2 + half; r < n; r += gridDim.x * 2) {
    float v = b2f(h[(size_t)r * 128 + f]);
    s += v; q += v * v;
  }
  __shared__ float red[512];
  red[t] = s; red[256 + t] = q; __syncthreads();
  if (t < 128) {
    atomicAdd(&stats[f],       red[t] + red[t + 128]);
    atomicAdd(&stats[128 + f], red[256 + t] + red[256 + t + 128]);
  }
}

__global__ void k_cnt(const int* __restrict__ batch, int* __restrict__ cnt, int n)
{
  int i = blockIdx.x * 256 + threadIdx.x;
  if (i < n) atomicAdd(&cnt[batch[i]], 1);
}

// ---------------- exclusive scan of cnt[B] -> gofs (single block) ----------------
__global__ void k_gofs(const int* __restrict__ cnt, int* __restrict__ gofs, int B)
{
  __shared__ int s[256];
  const int t = threadIdx.x;
  const int per = (B + 255) / 256;
  const int base = t * per;
  int loc[8]; int sum = 0;
  for (int j = 0; j < per; j++) { int v = (base + j < B) ? cnt[base + j] : 0; loc[j] = sum; sum += v; }
  s[t] = sum; __syncthreads();
  for (int o = 1; o < 256; o <<= 1) {
    int x = (t >= o) ? s[t - o] : 0;
    __syncthreads();
    s[t] += x;
    __syncthreads();
  }
  const int ex = s[t] - sum;
  for (int j = 0; j < per; j++) if (base + j < B) gofs[base + j] = ex + loc[j];
}

// ---- fold BN0 into W1: W1p = diag(a0) W1 (hi/lo bf16, transposed), b1p = c0@W1 + b1 ----
__global__ void k_prep1(const float* __restrict__ stats0, const float* __restrict__ W1,
                        const float* __restrict__ b1, const float* __restrict__ g0,
                        const float* __restrict__ be0, u16* __restrict__ W1hiT,
                        u16* __restrict__ W1loT, float* __restrict__ b1p, float n)
{
  __shared__ float A[128], Csh[128];
  const int t = threadIdx.x;  // 128 threads
  const float mu = stats0[t] / n;
  const float var = fmaxf(stats0[128 + t] / n - mu * mu, 0.f);
  const float a = g0[t] * rsqrtf(var + EPS);
  A[t] = a; Csh[t] = be0[t] - mu * a;
  __syncthreads();
  float acc = b1[t];
  for (int k = 0; k < 128; k++) {
    const float w0 = W1[k * 128 + t];
    acc += Csh[k] * w0;
    const float w = A[k] * w0;
    const u16 h = f2b(w);
    W1hiT[t * 128 + k] = h;
    W1loT[t * 128 + k] = f2b(w - b2f(h));
  }
  b1p[t] = acc;
}

// ---------------- fold BN1/BN2 + concat + W3 into w1f,w2f,constS ----------------
__global__ void k_prep2(const float* __restrict__ stats1, const float* __restrict__ stats2,
                        const float* __restrict__ g1, const float* __restrict__ be1,
                        const float* __restrict__ g2, const float* __restrict__ be2,
                        const float* __restrict__ W3, const float* __restrict__ b3,
                        float* __restrict__ w1f, float* __restrict__ w2f,
                        float* __restrict__ constS, float n)
{
  __shared__ float red[256];
  const int t = threadIdx.x;  // 256 threads
  float c, wv;
  if (t < 128) {
    const float mu = stats1[t] / n;
    const float var = fmaxf(stats1[128 + t] / n - mu * mu, 0.f);
    const float a = g1[t] * rsqrtf(var + EPS);
    c = be1[t] - mu * a;
    wv = W3[t];
    w1f[t] = a * wv;
  } else {
    const int f = t - 128;
    const float mu = stats2[f] / n;
    const float var = fmaxf(stats2[128 + f] / n - mu * mu, 0.f);
    const float a = g2[f] * rsqrtf(var + EPS);
    c = be2[f] - mu * a;
    wv = W3[t];
    w2f[f] = a * wv;
  }
  red[t] = c * wv; __syncthreads();
  for (int o = 128; o; o >>= 1) { if (t < o) red[t] += red[t + o]; __syncthreads(); }
  if (t == 0) { constS[0] = red[0] + b3[0]; constS[1] = b3[0]; }
}

// ---------------- per-node dot: s[n] = h1[n].w1f + h2[n].w2f ----------------
__global__ __launch_bounds__(256) void k_dot(const u16* __restrict__ h1, const u16* __restrict__ h2,
                                             const float* __restrict__ w1f, const float* __restrict__ w2f,
                                             float* __restrict__ s, int n)
{
  const int lane = threadIdx.x & 63;
  const int wid  = (blockIdx.x * 256 + threadIdx.x) >> 6;
  const int nw   = gridDim.x * 4;
  const float a0 = w1f[2 * lane], a1 = w1f[2 * lane + 1];
  const float c0 = w2f[2 * lane], c1 = w2f[2 * lane + 1];
  for (int node = wid; node < n; node += nw) {
    const u32 v1 = *(const u32*)(h1 + (size_t)node * 128 + 2 * lane);
    const u32 v2 = *(const u32*)(h2 + (size_t)node * 128 + 2 * lane);
    float d = b2f((u16)v1) * a0 + b2f((u16)(v1 >> 16)) * a1
            + b2f((u16)v2) * c0 + b2f((u16)(v2 >> 16)) * c1;
#pragma unroll
    for (int o = 1; o < 64; o <<= 1) d += __shfl_xor(d, o, 64);
    if (lane == 0) s[node] = d;
  }
}

// ---------------- per-graph mean + head ----------------
__global__ void k_out(const float* __restrict__ s, const int* __restrict__ gofs,
                      const int* __restrict__ cnt, const float* __restrict__ constS,
                      float* __restrict__ out, int B)
{
  const int lane = threadIdx.x & 63;
  const int g = (blockIdx.x * 256 + threadIdx.x) >> 6;
  if (g >= B) return;
  const int st = gofs[g], c = cnt[g];
  float acc = 0.f;
  for (int i = st + lane; i < st + c; i += 64) acc += s[i];
#pragma unroll
  for (int o = 1; o < 64; o <<= 1) acc += __shfl_xor(acc, o, 64);
  if (lane == 0) out[g] = (c > 0) ? acc / (float)c + constS[0] : constS[1];
}

extern "C" void kernel_launch(void* const* d_in, const int* in_sizes, int n_in,
                              void* d_out, int out_size, void* d_ws, size_t ws_size,
                              hipStream_t stream)
{
  const float* x    = (const float*)d_in[0];
  const float* act  = (const float*)d_in[1];
  const float* Wg   = (const float*)d_in[2];
  const float* bg   = (const float*)d_in[3];
  const float* g0   = (const float*)d_in[4];
  const float* be0  = (const float*)d_in[5];
  const float* W1   = (const float*)d_in[6];
  const float* b1   = (const float*)d_in[7];
  const float* g1   = (const float*)d_in[8];
  const float* be1  = (const float*)d_in[9];
  const float* W2   = (const float*)d_in[10];
  const float* b2   = (const float*)d_in[11];
  const float* g2   = (const float*)d_in[12];
  const float* be2  = (const float*)d_in[13];
  const float* W3   = (const float*)d_in[14];
  const float* b3   = (const float*)d_in[15];
  const int* eidx   = (const int*)d_in[16];
  const int* batch  = (const int*)d_in[17];

  const int N = in_sizes[17];          // 200000
  const int E = in_sizes[16] / 2;      // 1600000
  const int B = out_size;              // 1000
  const int* src = eidx;
  const int* dst = eidx + E;

  char* ws = (char*)d_ws;
  size_t off = 0;
  auto alloc = [&](size_t bytes) -> char* {
    off = (off + 255) & ~(size_t)255;
    char* p = ws + off; off += bytes; return p;
  };

  u16* bufA = (u16*)alloc((size_t)N * 128 * 2);   // h0, later h2
  u16* h1   = (u16*)alloc((size_t)N * 128 * 2);
  u16* xb   = (u16*)alloc((size_t)N * 64 * 2);    // bf16 x, later s (f32 N)
  u16* aggx = (u16*)alloc((size_t)N * 64 * 2);

  const size_t zbytes = (size_t)N * 4 + 3 * 256 * 4 + (size_t)B * 4;
  char* zbase   = alloc(zbytes);
  int*   deg    = (int*)zbase;
  float* stats0 = (float*)(zbase + (size_t)N * 4);
  float* stats1 = stats0 + 256;
  float* stats2 = stats1 + 256;
  int*   cnt    = (int*)(stats2 + 256);

  int*   offsets = (int*)alloc((size_t)(N + 1) * 4);
  int*   cursor  = (int*)alloc((size_t)N * 4);
  float* dinv    = (float*)alloc((size_t)N * 4);
  int*   elist   = (int*)alloc((size_t)(E + N) * 4);
  int*   bsum    = (int*)alloc(256 * 4);
  int*   bofs    = (int*)alloc(256 * 4);
  int*   gofs    = (int*)alloc((size_t)B * 4);
  u16*   WghiT   = (u16*)alloc(128 * 64 * 2);
  u16*   WgloT   = (u16*)alloc(128 * 64 * 2);
  u16*   W1hiT   = (u16*)alloc(128 * 128 * 2);
  u16*   W1loT   = (u16*)alloc(128 * 128 * 2);
  u16*   W2hiT   = (u16*)alloc(128 * 32 * 2);
  u16*   W2loT   = (u16*)alloc(128 * 32 * 2);
  float* b1p     = (float*)alloc(128 * 4);
  float* w1f     = (float*)alloc(128 * 4);
  float* w2f     = (float*)alloc(128 * 4);
  float* constS  = (float*)alloc(2 * 4);

  u16* h0 = bufA;
  u16* h2 = bufA;            // h0 dead after GEMM-h1 which precedes GEMM-h2
  float* s = (float*)xb;     // xb dead after k_agg

  hipMemsetAsync(zbase, 0, zbytes, stream);

  const int nscan = (N + 2047) / 2048;

  // weight prep + x cast
  k_split<<<(64 * 128 + 255) / 256, 256, 0, stream>>>(Wg, WghiT, WgloT, 64);
  k_split<<<(32 * 128 + 255) / 256, 256, 0, stream>>>(W2, W2hiT, W2loT, 32);
  k_cast<<<(N * 64 / 8 + 255) / 256, 256, 0, stream>>>(x, xb, N * 64);
  // CSR build (self-loops included)
  k_deg<<<(E + 255) / 256, 256, 0, stream>>>(dst, deg, E);
  k_scan1<<<nscan, 256, 0, stream>>>(deg, bsum, N);
  k_scan2<<<1, 256, 0, stream>>>(bsum, bofs, nscan);
  k_scan3<<<nscan, 256, 0, stream>>>(deg, bofs, offsets, cursor, dinv, elist, N, E + N);
  k_scatter<<<(E + 255) / 256, 256, 0, stream>>>(src, dst, cursor, elist, E);
  // aggregate x (64 feats), then GEMM with fused bias+relu -> h0
  k_agg<<<2048, 256, 0, stream>>>(xb, offsets, elist, dinv, aggx, N);
  k_gemm<64, true, true, false><<<1024, 256, 0, stream>>>(aggx, WghiT, WgloT, bg, h0, N);
  k_stats<<<1024, 256, 0, stream>>>(h0, stats0, N);
  k_cnt<<<(N + 255) / 256, 256, 0, stream>>>(batch, cnt, N);
  k_gofs<<<1, 256, 0, stream>>>(cnt, gofs, B);
  // fold BN0 into W1; h1 = relu(h0n @ W1 + b1)
  k_prep1<<<1, 128, 0, stream>>>(stats0, W1, b1, g0, be0, W1hiT, W1loT, b1p, (float)N);
  k_gemm<128, true, true, false><<<1024, 256, 0, stream>>>(h0, W1hiT, W1loT, b1p, h1, N);
  k_stats<<<1024, 256, 0, stream>>>(h1, stats1, N);
  // h2 = relu(action @ W2 + b2)
  k_gemm<32, true, true, true><<<1024, 256, 0, stream>>>(act, W2hiT, W2loT, b2, h2, N);
  k_stats<<<1024, 256, 0, stream>>>(h2, stats2, N);
  // fold BN1/BN2 + W3; pooled dot; output
  k_prep2<<<1, 256, 0, stream>>>(stats1, stats2, g1, be1, g2, be2, W3, b3, w1f, w2f, constS, (float)N);
  k_dot<<<1024, 256, 0, stream>>>(h1, h2, w1f, w2f, s, N);
  k_out<<<(B * 64 + 255) / 256, 256, 0, stream>>>(s, gofs, cnt, constS, (float*)d_out, B);
}

// Round 4
// 732.510 us; speedup vs baseline: 1.2622x; 1.1128x over previous
//
#include <hip/hip_runtime.h>

typedef unsigned short u16;
typedef unsigned int   u32;
typedef __bf16 bf16x8 __attribute__((ext_vector_type(8)));
typedef float  f32x4  __attribute__((ext_vector_type(4)));

#define EPS 1e-5f
#define BSHIFT 9               // 512 node ids per bucket

__device__ __forceinline__ float b2f(u16 u){ union{u32 i; float f;} v; v.i=((u32)u)<<16; return v.f; }
__device__ __forceinline__ u16 f2b(float f){
  u32 x = __float_as_uint(f);
  u32 r = x + 0x7fffu + ((x>>16)&1u);   // round-to-nearest-even
  return (u16)(r>>16);
}

// ---------------- GEMM: C[M,128] = act(A[M,K] @ (Bhi+Blo) + bias) ----------------
// B pre-split hi/lo bf16, pre-transposed [128,K]; staged once into LDS with XOR
// swizzle. Wave computes 16 rows x 128 cols via 16x16x32 MFMA, hi+lo weights.
template<int K, bool RELU, bool HASBIAS, bool AF32>
__global__ __launch_bounds__(256) void k_gemm(const void* __restrict__ Av,
                                              const u16* __restrict__ BhiT,
                                              const u16* __restrict__ BloT,
                                              const float* __restrict__ bias,
                                              u16* __restrict__ C, int M)
{
  constexpr int KM = K / 8;                 // 8-elem blocks per row
  __shared__ u16 lds[2 * 128 * K];          // [hi|lo][128 cols][K swizzled]
  const int tid = threadIdx.x;
  for (int i = tid; i < 128 * KM; i += 256) {
    const int n = i / KM, kb = i % KM;
    const int kb2 = kb ^ (n & (KM - 1));
    *(uint4*)(&lds[(n * KM + kb2) * 8])           = *(const uint4*)(BhiT + i * 8);
    *(uint4*)(&lds[128 * K + (n * KM + kb2) * 8]) = *(const uint4*)(BloT + i * 8);
  }
  __syncthreads();
  const int wid = tid >> 6, lane = tid & 63, q = lane >> 4, r16 = lane & 15;
  const int ntiles = M >> 6;                // M divisible by 64 (200000 = 3125*64)
  for (int tile = blockIdx.x; tile < ntiles; tile += gridDim.x) {
    const int arow = (tile << 6) + (wid << 4) + r16;
    bf16x8 av[K / 32];
    if (AF32) {
      const float* Af = (const float*)Av + (size_t)arow * K + q * 8;
#pragma unroll
      for (int kk = 0; kk < K / 32; kk++) {
        f32x4 x0 = *(const f32x4*)(Af + kk * 32);
        f32x4 x1 = *(const f32x4*)(Af + kk * 32 + 4);
#pragma unroll
        for (int j = 0; j < 4; j++) { av[kk][j] = (__bf16)x0[j]; av[kk][4 + j] = (__bf16)x1[j]; }
      }
    } else {
      const u16* Ab = (const u16*)Av + (size_t)arow * K + q * 8;
#pragma unroll
      for (int kk = 0; kk < K / 32; kk++) av[kk] = *(const bf16x8*)(Ab + kk * 32);
    }
    f32x4 acc[8];
#pragma unroll
    for (int nb = 0; nb < 8; nb++) acc[nb] = (f32x4){0.f, 0.f, 0.f, 0.f};
#pragma unroll
    for (int kk = 0; kk < K / 32; kk++) {
#pragma unroll
      for (int nb = 0; nb < 8; nb++) {
        const int n = nb * 16 + r16;
        const int kb2 = (kk * 4 + q) ^ (n & (KM - 1));
        const bf16x8 bh = *(const bf16x8*)(&lds[(n * KM + kb2) * 8]);
        const bf16x8 bl = *(const bf16x8*)(&lds[128 * K + (n * KM + kb2) * 8]);
        acc[nb] = __builtin_amdgcn_mfma_f32_16x16x32_bf16(av[kk], bh, acc[nb], 0, 0, 0);
        acc[nb] = __builtin_amdgcn_mfma_f32_16x16x32_bf16(av[kk], bl, acc[nb], 0, 0, 0);
      }
    }
    const int rbase = (tile << 6) + (wid << 4) + (q << 2);
#pragma unroll
    for (int nb = 0; nb < 8; nb++) {
      const int col = nb * 16 + r16;
      const float bv = HASBIAS ? bias[col] : 0.f;
#pragma unroll
      for (int r = 0; r < 4; r++) {
        float v = acc[nb][r] + bv;
        if (RELU) v = fmaxf(v, 0.f);
        C[(size_t)(rbase + r) * 128 + col] = f2b(v);
      }
    }
  }
}

// ---------------- split fp32 W[K,128] -> hi/lo bf16 transposed [128,K] ----------------
__global__ void k_split(const float* __restrict__ W, u16* __restrict__ hiT,
                        u16* __restrict__ loT, int K)
{
  int i = blockIdx.x * 256 + threadIdx.x;
  if (i < K * 128) {
    int k = i >> 7, n = i & 127;
    float w = W[i];
    u16 h = f2b(w);
    hiT[n * K + k] = h;
    loT[n * K + k] = f2b(w - b2f(h));
  }
}

// ---------------- cast x fp32 [N,64] -> bf16 ----------------
__global__ void k_cast(const float* __restrict__ x, u16* __restrict__ xb, int n)
{
  int i = (blockIdx.x * 256 + threadIdx.x) * 8;
  if (i < n) {
    f32x4 a = *(const f32x4*)(x + i);
    f32x4 b = *(const f32x4*)(x + i + 4);
    u16 o[8];
#pragma unroll
    for (int j = 0; j < 4; j++) { o[j] = f2b(a[j]); o[4 + j] = f2b(b[j]); }
    *(uint4*)(xb + i) = *(uint4*)o;
  }
}

// ========== binned edge partition (kills random-scatter write amplification) ==========
// Phase A: per-block LDS histogram of dst>>BSHIFT -> global bucket totals.
__global__ __launch_bounds__(256) void k_bincnt(const int* __restrict__ dst, int* __restrict__ btot,
                                                int E, int NB)
{
  extern __shared__ int hist[];
  const int tid = threadIdx.x;
  for (int i = tid; i < NB; i += 256) hist[i] = 0;
  __syncthreads();
  const int chunk = (E + gridDim.x - 1) / gridDim.x;
  const int start = blockIdx.x * chunk;
  const int end = min(start + chunk, E);
  for (int e = start + tid; e < end; e += 256) atomicAdd(&hist[((u32)dst[e]) >> BSHIFT], 1);
  __syncthreads();
  for (int i = tid; i < NB; i += 256) if (hist[i]) atomicAdd(&btot[i], hist[i]);
}

// generic single-block exclusive scan; out[0..n-1] = exclusive, out[n] = total (n<=2048)
__global__ void k_exscan(const int* __restrict__ in, int* __restrict__ out, int n)
{
  __shared__ int s[256];
  const int t = threadIdx.x;
  const int per = (n + 255) / 256;
  const int base = t * per;
  int loc[8]; int sum = 0;
  for (int j = 0; j < per; j++) { int v = (base + j < n) ? in[base + j] : 0; loc[j] = sum; sum += v; }
  s[t] = sum; __syncthreads();
  for (int o = 1; o < 256; o <<= 1) {
    int x = (t >= o) ? s[t - o] : 0;
    __syncthreads();
    s[t] += x;
    __syncthreads();
  }
  const int ex = s[t] - sum;
  for (int j = 0; j < per; j++) if (base + j < n) out[base + j] = ex + loc[j];
  if (t == 255) out[n] = s[255];
}

// Phase B: re-read edges, reserve per-(block,bucket) ranges, stream (dst,src) pairs.
__global__ __launch_bounds__(256) void k_bin(const int* __restrict__ src, const int* __restrict__ dst,
                                             const int* __restrict__ bbase, int* __restrict__ bcur,
                                             uint2* __restrict__ pairs, int E, int NB)
{
  extern __shared__ int lds[];
  int* hist = lds; int* wbase = lds + NB;
  const int tid = threadIdx.x;
  for (int i = tid; i < NB; i += 256) hist[i] = 0;
  __syncthreads();
  const int chunk = (E + gridDim.x - 1) / gridDim.x;
  const int start = blockIdx.x * chunk;
  const int end = min(start + chunk, E);
  for (int e = start + tid; e < end; e += 256) atomicAdd(&hist[((u32)dst[e]) >> BSHIFT], 1);
  __syncthreads();
  for (int i = tid; i < NB; i += 256) {
    int c = hist[i];
    wbase[i] = c ? bbase[i] + atomicAdd(&bcur[i], c) : 0;
    hist[i] = 0;
  }
  __syncthreads();
  for (int e = start + tid; e < end; e += 256) {
    const int d = dst[e];
    const int b = ((u32)d) >> BSHIFT;
    const int o = atomicAdd(&hist[b], 1);
    pairs[wbase[b] + o] = make_uint2((u32)d, (u32)src[e]);
  }
}

// Degrees via per-bucket LDS histogram; each bucket exclusively owns its node range
// -> plain stores, zero global atomics.
__global__ __launch_bounds__(256) void k_degloc(const uint2* __restrict__ pairs,
                                                const int* __restrict__ bbase,
                                                int* __restrict__ deg, int N)
{
  __shared__ int hist[1 << BSHIFT];
  const int tid = threadIdx.x;
  const int b = blockIdx.x;
  const int nbase = b << BSHIFT;
  const int nend = min(nbase + (1 << BSHIFT), N);
  for (int i = tid; i < (1 << BSHIFT); i += 256) hist[i] = 0;
  __syncthreads();
  const int p0 = bbase[b], p1 = bbase[b + 1];
  for (int p = p0 + tid; p < p1; p += 256) atomicAdd(&hist[pairs[p].x - nbase], 1);
  __syncthreads();
  for (int i = nbase + tid; i < nend; i += 256) deg[i] = hist[i - nbase];
}

// ------- prefix scan of (deg+1) incl. self-loops (3 kernels, 2048 elems/block) -------
__global__ void k_scan1(const int* __restrict__ deg, int* __restrict__ bsum, int n)
{
  __shared__ int s[256];
  const int t = threadIdx.x;
  const int base = blockIdx.x * 2048 + t * 8;
  int sum = 0;
#pragma unroll
  for (int j = 0; j < 8; j++) { int i = base + j; if (i < n) sum += deg[i] + 1; }
  s[t] = sum; __syncthreads();
  for (int o = 128; o; o >>= 1) { if (t < o) s[t] += s[t + o]; __syncthreads(); }
  if (t == 0) bsum[blockIdx.x] = s[0];
}

__global__ void k_scan2(const int* __restrict__ bsum, int* __restrict__ bofs, int nb)
{
  __shared__ int s[256];
  const int t = threadIdx.x;
  int v = (t < nb) ? bsum[t] : 0;
  s[t] = v; __syncthreads();
  for (int o = 1; o < 256; o <<= 1) {
    int x = (t >= o) ? s[t - o] : 0;
    __syncthreads();
    s[t] += x;
    __syncthreads();
  }
  if (t < nb) bofs[t] = s[t] - v;   // exclusive
}

// scan3 also seeds the self-loop edge (elist[off]=i) and sets cursor past it
__global__ void k_scan3(const int* __restrict__ deg, const int* __restrict__ bofs,
                        int* __restrict__ offsets, int* __restrict__ cursor,
                        float* __restrict__ dinv, int* __restrict__ elist, int n, int Etot)
{
  __shared__ int s[256];
  const int t = threadIdx.x;
  const int base = blockIdx.x * 2048 + t * 8;
  int loc[8]; int sum = 0;
#pragma unroll
  for (int j = 0; j < 8; j++) { int i = base + j; int d = (i < n) ? deg[i] + 1 : 0; loc[j] = sum; sum += d; }
  const int own = sum;
  s[t] = sum; __syncthreads();
  for (int o = 1; o < 256; o <<= 1) {
    int x = (t >= o) ? s[t - o] : 0;
    __syncthreads();
    s[t] += x;
    __syncthreads();
  }
  const int tbase = bofs[blockIdx.x] + s[t] - own;
#pragma unroll
  for (int j = 0; j < 8; j++) {
    int i = base + j;
    if (i < n) {
      int off = tbase + loc[j];
      offsets[i] = off;
      elist[off] = i;            // self-loop
      cursor[i] = off + 1;
      dinv[i] = rsqrtf((float)(deg[i] + 1));
      if (i == n - 1) offsets[n] = Etot;
    }
  }
}

// Phase C: per-bucket scatter into CSR; cursor atomics and elist writes confined to
// L2-resident windows (~2KB cursor / ~16KB elist per bucket).
__global__ __launch_bounds__(256) void k_scatter2(const uint2* __restrict__ pairs,
                                                  const int* __restrict__ bbase,
                                                  int* __restrict__ cursor, int* __restrict__ elist)
{
  const int b = blockIdx.x;
  const int p0 = bbase[b], p1 = bbase[b + 1];
  for (int p = p0 + threadIdx.x; p < p1; p += 256) {
    const uint2 pr = pairs[p];
    const int pos = atomicAdd(&cursor[pr.x], 1);
    elist[pos] = (int)pr.y;
  }
}

// ------- GCN aggregation on x (64 bf16 feats, 128B rows): agg commutes with W -------
__global__ __launch_bounds__(256) void k_agg(const u16* __restrict__ xb, const int* __restrict__ offsets,
                                             const int* __restrict__ elist, const float* __restrict__ dinv,
                                             u16* __restrict__ aggx, int n)
{
  const int lane = threadIdx.x & 63;
  const int half = lane >> 5, l32 = lane & 31;
  const int wid  = (blockIdx.x * 256 + threadIdx.x) >> 6;
  const int nw   = gridDim.x * 4;
  for (int node = wid; node < n; node += nw) {
    const int s0 = offsets[node], s1 = offsets[node + 1];
    const float di = dinv[node];
    float a0 = 0.f, a1 = 0.f;
    for (int p = s0; p < s1; p += 2) {
      const int pi = p + half;
      if (pi < s1) {
        const int sidx = elist[pi];
        const float w = dinv[sidx];
        const u32 v = *(const u32*)(xb + (size_t)sidx * 64 + 2 * l32);
        a0 += b2f((u16)v) * w; a1 += b2f((u16)(v >> 16)) * w;
      }
    }
    a0 += __shfl_xor(a0, 32, 64);
    a1 += __shfl_xor(a1, 32, 64);
    if (half == 0) {
      const u32 o = (u32)f2b(a0 * di) | ((u32)f2b(a1 * di) << 16);
      *(u32*)(aggx + (size_t)node * 64 + 2 * l32) = o;
    }
  }
}

// ---------------- BN stats: per-feature sum & sumsq over N rows ----------------
__global__ __launch_bounds__(256) void k_stats(const u16* __restrict__ h, float* __restrict__ stats, int n)
{
  const int t = threadIdx.x, f = t & 127, half = t >> 7;
  float s = 0.f, q = 0.f;
  for (int r = blockIdx.x * 2 + half; r < n; r += gridDim.x * 2) {
    float v = b2f(h[(size_t)r * 128 + f]);
    s += v; q += v * v;
  }
  __shared__ float red[512];
  red[t] = s; red[256 + t] = q; __syncthreads();
  if (t < 128) {
    atomicAdd(&stats[f],       red[t] + red[t + 128]);
    atomicAdd(&stats[128 + f], red[256 + t] + red[256 + t + 128]);
  }
}

__global__ void k_cnt(const int* __restrict__ batch, int* __restrict__ cnt, int n)
{
  int i = blockIdx.x * 256 + threadIdx.x;
  if (i < n) atomicAdd(&cnt[batch[i]], 1);
}

// ---- fold BN0 into W1: W1p = diag(a0) W1 (hi/lo bf16, transposed), b1p = c0@W1 + b1 ----
__global__ void k_prep1(const float* __restrict__ stats0, const float* __restrict__ W1,
                        const float* __restrict__ b1, const float* __restrict__ g0,
                        const float* __restrict__ be0, u16* __restrict__ W1hiT,
                        u16* __restrict__ W1loT, float* __restrict__ b1p, float n)
{
  __shared__ float A[128], Csh[128];
  const int t = threadIdx.x;  // 128 threads
  const float mu = stats0[t] / n;
  const float var = fmaxf(stats0[128 + t] / n - mu * mu, 0.f);
  const float a = g0[t] * rsqrtf(var + EPS);
  A[t] = a; Csh[t] = be0[t] - mu * a;
  __syncthreads();
  float acc = b1[t];
  for (int k = 0; k < 128; k++) {
    const float w0 = W1[k * 128 + t];
    acc += Csh[k] * w0;
    const float w = A[k] * w0;
    const u16 h = f2b(w);
    W1hiT[t * 128 + k] = h;
    W1loT[t * 128 + k] = f2b(w - b2f(h));
  }
  b1p[t] = acc;
}

// ---------------- fold BN1/BN2 + concat + W3 into w1f,w2f,constS ----------------
__global__ void k_prep2(const float* __restrict__ stats1, const float* __restrict__ stats2,
                        const float* __restrict__ g1, const float* __restrict__ be1,
                        const float* __restrict__ g2, const float* __restrict__ be2,
                        const float* __restrict__ W3, const float* __restrict__ b3,
                        float* __restrict__ w1f, float* __restrict__ w2f,
                        float* __restrict__ constS, float n)
{
  __shared__ float red[256];
  const int t = threadIdx.x;  // 256 threads
  float c, wv;
  if (t < 128) {
    const float mu = stats1[t] / n;
    const float var = fmaxf(stats1[128 + t] / n - mu * mu, 0.f);
    const float a = g1[t] * rsqrtf(var + EPS);
    c = be1[t] - mu * a;
    wv = W3[t];
    w1f[t] = a * wv;
  } else {
    const int f = t - 128;
    const float mu = stats2[f] / n;
    const float var = fmaxf(stats2[128 + f] / n - mu * mu, 0.f);
    const float a = g2[f] * rsqrtf(var + EPS);
    c = be2[f] - mu * a;
    wv = W3[t];
    w2f[f] = a * wv;
  }
  red[t] = c * wv; __syncthreads();
  for (int o = 128; o; o >>= 1) { if (t < o) red[t] += red[t + o]; __syncthreads(); }
  if (t == 0) { constS[0] = red[0] + b3[0]; constS[1] = b3[0]; }
}

// ---------------- per-node dot: s[n] = h1[n].w1f + h2[n].w2f ----------------
__global__ __launch_bounds__(256) void k_dot(const u16* __restrict__ h1, const u16* __restrict__ h2,
                                             const float* __restrict__ w1f, const float* __restrict__ w2f,
                                             float* __restrict__ s, int n)
{
  const int lane = threadIdx.x & 63;
  const int wid  = (blockIdx.x * 256 + threadIdx.x) >> 6;
  const int nw   = gridDim.x * 4;
  const float a0 = w1f[2 * lane], a1 = w1f[2 * lane + 1];
  const float c0 = w2f[2 * lane], c1 = w2f[2 * lane + 1];
  for (int node = wid; node < n; node += nw) {
    const u32 v1 = *(const u32*)(h1 + (size_t)node * 128 + 2 * lane);
    const u32 v2 = *(const u32*)(h2 + (size_t)node * 128 + 2 * lane);
    float d = b2f((u16)v1) * a0 + b2f((u16)(v1 >> 16)) * a1
            + b2f((u16)v2) * c0 + b2f((u16)(v2 >> 16)) * c1;
#pragma unroll
    for (int o = 1; o < 64; o <<= 1) d += __shfl_xor(d, o, 64);
    if (lane == 0) s[node] = d;
  }
}

// ---------------- per-graph mean + head ----------------
__global__ void k_out(const float* __restrict__ s, const int* __restrict__ gofs,
                      const int* __restrict__ cnt, const float* __restrict__ constS,
                      float* __restrict__ out, int B)
{
  const int lane = threadIdx.x & 63;
  const int g = (blockIdx.x * 256 + threadIdx.x) >> 6;
  if (g >= B) return;
  const int st = gofs[g], c = cnt[g];
  float acc = 0.f;
  for (int i = st + lane; i < st + c; i += 64) acc += s[i];
#pragma unroll
  for (int o = 1; o < 64; o <<= 1) acc += __shfl_xor(acc, o, 64);
  if (lane == 0) out[g] = (c > 0) ? acc / (float)c + constS[0] : constS[1];
}

extern "C" void kernel_launch(void* const* d_in, const int* in_sizes, int n_in,
                              void* d_out, int out_size, void* d_ws, size_t ws_size,
                              hipStream_t stream)
{
  const float* x    = (const float*)d_in[0];
  const float* act  = (const float*)d_in[1];
  const float* Wg   = (const float*)d_in[2];
  const float* bg   = (const float*)d_in[3];
  const float* g0   = (const float*)d_in[4];
  const float* be0  = (const float*)d_in[5];
  const float* W1   = (const float*)d_in[6];
  const float* b1   = (const float*)d_in[7];
  const float* g1   = (const float*)d_in[8];
  const float* be1  = (const float*)d_in[9];
  const float* W2   = (const float*)d_in[10];
  const float* b2   = (const float*)d_in[11];
  const float* g2   = (const float*)d_in[12];
  const float* be2  = (const float*)d_in[13];
  const float* W3   = (const float*)d_in[14];
  const float* b3   = (const float*)d_in[15];
  const int* eidx   = (const int*)d_in[16];
  const int* batch  = (const int*)d_in[17];

  const int N = in_sizes[17];          // 200000
  const int E = in_sizes[16] / 2;      // 1600000
  const int B = out_size;              // 1000
  const int* src = eidx;
  const int* dst = eidx + E;
  const int NB = (N + (1 << BSHIFT) - 1) >> BSHIFT;   // ~391 buckets

  char* ws = (char*)d_ws;
  size_t off = 0;
  auto alloc = [&](size_t bytes) -> char* {
    off = (off + 255) & ~(size_t)255;
    char* p = ws + off; off += bytes; return p;
  };

  u16* bufA = (u16*)alloc((size_t)N * 128 * 2);   // h0, later h2
  u16* h1   = (u16*)alloc((size_t)N * 128 * 2);
  u16* xb   = (u16*)alloc((size_t)N * 64 * 2);    // bf16 x, later s (f32 N)
  u16* aggx = (u16*)alloc((size_t)N * 64 * 2);

  const size_t zbytes = (size_t)N * 4 + 768 * 4 + (size_t)B * 4 + 2 * (size_t)NB * 4;
  char* zbase   = alloc(zbytes);
  int*   deg    = (int*)zbase;
  float* stats0 = (float*)(zbase + (size_t)N * 4);
  float* stats1 = stats0 + 256;
  float* stats2 = stats1 + 256;
  int*   cnt    = (int*)(stats2 + 256);
  int*   btot   = cnt + B;
  int*   bcur   = btot + NB;

  int*   offsets = (int*)alloc((size_t)(N + 1) * 4);
  int*   cursor  = (int*)alloc((size_t)N * 4);
  float* dinv    = (float*)alloc((size_t)N * 4);
  int*   elist   = (int*)alloc((size_t)(E + N) * 4);
  uint2* pairs   = (uint2*)alloc((size_t)E * 8);
  int*   bbase   = (int*)alloc((size_t)(NB + 1) * 4);
  int*   bsum    = (int*)alloc(256 * 4);
  int*   bofs    = (int*)alloc(256 * 4);
  int*   gofs    = (int*)alloc((size_t)(B + 1) * 4);
  u16*   WghiT   = (u16*)alloc(128 * 64 * 2);
  u16*   WgloT   = (u16*)alloc(128 * 64 * 2);
  u16*   W1hiT   = (u16*)alloc(128 * 128 * 2);
  u16*   W1loT   = (u16*)alloc(128 * 128 * 2);
  u16*   W2hiT   = (u16*)alloc(128 * 32 * 2);
  u16*   W2loT   = (u16*)alloc(128 * 32 * 2);
  float* b1p     = (float*)alloc(128 * 4);
  float* w1f     = (float*)alloc(128 * 4);
  float* w2f     = (float*)alloc(128 * 4);
  float* constS  = (float*)alloc(2 * 4);

  u16* h0 = bufA;
  u16* h2 = bufA;            // h0 dead after GEMM-h1 which precedes GEMM-h2
  float* s = (float*)xb;     // xb dead after k_agg

  hipMemsetAsync(zbase, 0, zbytes, stream);

  const int nscan = (N + 2047) / 2048;

  // weight prep + x cast
  k_split<<<(64 * 128 + 255) / 256, 256, 0, stream>>>(Wg, WghiT, WgloT, 64);
  k_split<<<(32 * 128 + 255) / 256, 256, 0, stream>>>(W2, W2hiT, W2loT, 32);
  k_cast<<<(N * 64 / 8 + 255) / 256, 256, 0, stream>>>(x, xb, N * 64);
  // binned edge partition
  k_bincnt<<<256, 256, NB * 4, stream>>>(dst, btot, E, NB);
  k_exscan<<<1, 256, 0, stream>>>(btot, bbase, NB);
  k_bin<<<256, 256, 2 * NB * 4, stream>>>(src, dst, bbase, bcur, pairs, E, NB);
  k_degloc<<<NB, 256, 0, stream>>>(pairs, bbase, deg, N);
  // CSR offsets (self-loops included)
  k_scan1<<<nscan, 256, 0, stream>>>(deg, bsum, N);
  k_scan2<<<1, 256, 0, stream>>>(bsum, bofs, nscan);
  k_scan3<<<nscan, 256, 0, stream>>>(deg, bofs, offsets, cursor, dinv, elist, N, E + N);
  k_scatter2<<<NB, 256, 0, stream>>>(pairs, bbase, cursor, elist);
  // aggregate x (64 feats), then GEMM with fused bias+relu -> h0
  k_agg<<<2048, 256, 0, stream>>>(xb, offsets, elist, dinv, aggx, N);
  k_gemm<64, true, true, false><<<1024, 256, 0, stream>>>(aggx, WghiT, WgloT, bg, h0, N);
  k_stats<<<1024, 256, 0, stream>>>(h0, stats0, N);
  k_cnt<<<(N + 255) / 256, 256, 0, stream>>>(batch, cnt, N);
  k_exscan<<<1, 256, 0, stream>>>(cnt, gofs, B);
  // fold BN0 into W1; h1 = relu(h0n @ W1 + b1)
  k_prep1<<<1, 128, 0, stream>>>(stats0, W1, b1, g0, be0, W1hiT, W1loT, b1p, (float)N);
  k_gemm<128, true, true, false><<<1024, 256, 0, stream>>>(h0, W1hiT, W1loT, b1p, h1, N);
  k_stats<<<1024, 256, 0, stream>>>(h1, stats1, N);
  // h2 = relu(action @ W2 + b2)
  k_gemm<32, true, true, true><<<1024, 256, 0, stream>>>(act, W2hiT, W2loT, b2, h2, N);
  k_stats<<<1024, 256, 0, stream>>>(h2, stats2, N);
  // fold BN1/BN2 + W3; pooled dot; output
  k_prep2<<<1, 256, 0, stream>>>(stats1, stats2, g1, be1, g2, be2, W3, b3, w1f, w2f, constS, (float)N);
  k_dot<<<1024, 256, 0, stream>>>(h1, h2, w1f, w2f, s, N);
  k_out<<<(B * 64 + 255) / 256, 256, 0, stream>>>(s, gofs, cnt, constS, (float*)d_out, B);
}

// Round 7
// 593.887 us; speedup vs baseline: 1.5569x; 1.2334x over previous
//
#include <hip/hip_runtime.h>

typedef unsigned short u16;
typedef unsigned int   u32;
typedef __bf16 bf16x8 __attribute__((ext_vector_type(8)));
typedef float  f32x4  __attribute__((ext_vector_type(4)));

#define EPS 1e-5f
#define BSHIFT 9               // 512 node ids per bucket

__device__ __forceinline__ float b2f(u16 u){ union{u32 i; float f;} v; v.i=((u32)u)<<16; return v.f; }
__device__ __forceinline__ u16 f2b(float f){
  u32 x = __float_as_uint(f);
  u32 r = x + 0x7fffu + ((x>>16)&1u);   // round-to-nearest-even
  return (u16)(r>>16);
}

// ---- GEMM: C[M,128] = act(A[M,K] @ (Bhi+Blo) + bias) ---- (round-4 verified form)
template<int K, bool RELU, bool HASBIAS, bool AF32>
__global__ __launch_bounds__(256) void k_gemm(const void* __restrict__ Av,
                                              const u16* __restrict__ BhiT,
                                              const u16* __restrict__ BloT,
                                              const float* __restrict__ bias,
                                              u16* __restrict__ C, int M)
{
  constexpr int KM = K / 8;                 // 8-elem blocks per row
  __shared__ u16 lds[2 * 128 * K];          // [hi|lo][128 cols][K swizzled]
  const int tid = threadIdx.x;
  for (int i = tid; i < 128 * KM; i += 256) {
    const int n = i / KM, kb = i % KM;
    const int kb2 = kb ^ (n & (KM - 1));
    *(uint4*)(&lds[(n * KM + kb2) * 8])           = *(const uint4*)(BhiT + i * 8);
    *(uint4*)(&lds[128 * K + (n * KM + kb2) * 8]) = *(const uint4*)(BloT + i * 8);
  }
  __syncthreads();
  const int wid = tid >> 6, lane = tid & 63, q = lane >> 4, r16 = lane & 15;
  const int ntiles = M >> 6;                // M divisible by 64 (200000 = 3125*64)
  for (int tile = blockIdx.x; tile < ntiles; tile += gridDim.x) {
    const int arow = (tile << 6) + (wid << 4) + r16;
    bf16x8 av[K / 32];
    if (AF32) {
      const float* Af = (const float*)Av + (size_t)arow * K + q * 8;
#pragma unroll
      for (int kk = 0; kk < K / 32; kk++) {
        f32x4 x0 = *(const f32x4*)(Af + kk * 32);
        f32x4 x1 = *(const f32x4*)(Af + kk * 32 + 4);
#pragma unroll
        for (int j = 0; j < 4; j++) { av[kk][j] = (__bf16)x0[j]; av[kk][4 + j] = (__bf16)x1[j]; }
      }
    } else {
      const u16* Ab = (const u16*)Av + (size_t)arow * K + q * 8;
#pragma unroll
      for (int kk = 0; kk < K / 32; kk++) av[kk] = *(const bf16x8*)(Ab + kk * 32);
    }
    f32x4 acc[8];
#pragma unroll
    for (int nb = 0; nb < 8; nb++) acc[nb] = (f32x4){0.f, 0.f, 0.f, 0.f};
#pragma unroll
    for (int kk = 0; kk < K / 32; kk++) {
#pragma unroll
      for (int nb = 0; nb < 8; nb++) {
        const int n = nb * 16 + r16;
        const int kb2 = (kk * 4 + q) ^ (n & (KM - 1));
        const bf16x8 bh = *(const bf16x8*)(&lds[(n * KM + kb2) * 8]);
        const bf16x8 bl = *(const bf16x8*)(&lds[128 * K + (n * KM + kb2) * 8]);
        acc[nb] = __builtin_amdgcn_mfma_f32_16x16x32_bf16(av[kk], bh, acc[nb], 0, 0, 0);
        acc[nb] = __builtin_amdgcn_mfma_f32_16x16x32_bf16(av[kk], bl, acc[nb], 0, 0, 0);
      }
    }
    const int rbase = (tile << 6) + (wid << 4) + (q << 2);
#pragma unroll
    for (int nb = 0; nb < 8; nb++) {
      const int col = nb * 16 + r16;
      const float bv = HASBIAS ? bias[col] : 0.f;
#pragma unroll
      for (int r = 0; r < 4; r++) {
        float v = acc[nb][r] + bv;
        if (RELU) v = fmaxf(v, 0.f);
        C[(size_t)(rbase + r) * 128 + col] = f2b(v);
      }
    }
  }
}

// ---- split fp32 Wg[64,128] and W2[32,128] -> hi/lo bf16 transposed, one launch ----
__global__ void k_splitall(const float* __restrict__ Wg, const float* __restrict__ W2,
                           u16* __restrict__ WghiT, u16* __restrict__ WgloT,
                           u16* __restrict__ W2hiT, u16* __restrict__ W2loT)
{
  int i = blockIdx.x * 256 + threadIdx.x;
  if (i < 64 * 128) {
    int k = i >> 7, n = i & 127;
    float w = Wg[i]; u16 h = f2b(w);
    WghiT[n * 64 + k] = h; WgloT[n * 64 + k] = f2b(w - b2f(h));
  } else if (i < 64 * 128 + 32 * 128) {
    int j = i - 64 * 128;
    int k = j >> 7, n = j & 127;
    float w = W2[j]; u16 h = f2b(w);
    W2hiT[n * 32 + k] = h; W2loT[n * 32 + k] = f2b(w - b2f(h));
  }
}

// ---------------- cast + premultiply: y[i][f] = bf16(x[i][f] * dinv[i]) ----------------
__global__ void k_cast(const float* __restrict__ x, const float* __restrict__ dinv,
                       u16* __restrict__ y, int n)
{
  int i = (blockIdx.x * 256 + threadIdx.x) * 8;
  if (i < n) {
    const float d = dinv[i >> 6];
    f32x4 a = *(const f32x4*)(x + i);
    f32x4 b = *(const f32x4*)(x + i + 4);
    u16 o[8];
#pragma unroll
    for (int j = 0; j < 4; j++) { o[j] = f2b(a[j] * d); o[4 + j] = f2b(b[j] * d); }
    *(uint4*)(y + i) = *(uint4*)o;
  }
}

// ========== binned edge partition (round-4 verified chain) ==========
__global__ __launch_bounds__(256) void k_bincnt(const int* __restrict__ dst, int* __restrict__ btot,
                                                int E, int NB)
{
  extern __shared__ int hist[];
  const int tid = threadIdx.x;
  for (int i = tid; i < NB; i += 256) hist[i] = 0;
  __syncthreads();
  const int chunk = (E + gridDim.x - 1) / gridDim.x;
  const int start = blockIdx.x * chunk;
  const int end = min(start + chunk, E);
  for (int e = start + tid; e < end; e += 256) atomicAdd(&hist[((u32)dst[e]) >> BSHIFT], 1);
  __syncthreads();
  for (int i = tid; i < NB; i += 256) if (hist[i]) atomicAdd(&btot[i], hist[i]);
}

// single-block exclusive scan; out[0..n-1] = exclusive, out[n] = total
__global__ void k_exscan(const int* __restrict__ in, int* __restrict__ out, int n)
{
  __shared__ int s[256];
  const int t = threadIdx.x;
  const int per = (n + 255) / 256;
  const int base = t * per;
  int loc[8]; int sum = 0;
  for (int j = 0; j < per; j++) { int v = (base + j < n) ? in[base + j] : 0; loc[j] = sum; sum += v; }
  s[t] = sum; __syncthreads();
  for (int o = 1; o < 256; o <<= 1) {
    int x = (t >= o) ? s[t - o] : 0;
    __syncthreads();
    s[t] += x;
    __syncthreads();
  }
  const int ex = s[t] - sum;
  for (int j = 0; j < per; j++) if (base + j < n) out[base + j] = ex + loc[j];
  if (t == 255) out[n] = s[255];
}

// re-read edges, reserve per-(block,bucket) ranges, stream (dst,src) pairs
__global__ __launch_bounds__(256) void k_bin(const int* __restrict__ src, const int* __restrict__ dst,
                                             const int* __restrict__ bbase, int* __restrict__ bcur,
                                             uint2* __restrict__ pairs, int E, int NB)
{
  extern __shared__ int lds[];
  int* hist = lds; int* wbase = lds + NB;
  const int tid = threadIdx.x;
  for (int i = tid; i < NB; i += 256) hist[i] = 0;
  __syncthreads();
  const int chunk = (E + gridDim.x - 1) / gridDim.x;
  const int start = blockIdx.x * chunk;
  const int end = min(start + chunk, E);
  for (int e = start + tid; e < end; e += 256) atomicAdd(&hist[((u32)dst[e]) >> BSHIFT], 1);
  __syncthreads();
  for (int i = tid; i < NB; i += 256) {
    int c = hist[i];
    wbase[i] = c ? bbase[i] + atomicAdd(&bcur[i], c) : 0;
    hist[i] = 0;
  }
  __syncthreads();
  for (int e = start + tid; e < end; e += 256) {
    const int d = dst[e];
    const int b = ((u32)d) >> BSHIFT;
    const int o = atomicAdd(&hist[b], 1);
    pairs[wbase[b] + o] = make_uint2((u32)d, (u32)src[e]);
  }
}

// degrees via per-bucket LDS histogram; plain stores, zero global atomics
__global__ __launch_bounds__(256) void k_degloc(const uint2* __restrict__ pairs,
                                                const int* __restrict__ bbase,
                                                int* __restrict__ deg, int N)
{
  __shared__ int hist[1 << BSHIFT];
  const int tid = threadIdx.x;
  const int b = blockIdx.x;
  const int nbase = b << BSHIFT;
  const int nend = min(nbase + (1 << BSHIFT), N);
  for (int i = tid; i < (1 << BSHIFT); i += 256) hist[i] = 0;
  __syncthreads();
  const int p0 = bbase[b], p1 = bbase[b + 1];
  for (int p = p0 + tid; p < p1; p += 256) atomicAdd(&hist[pairs[p].x - nbase], 1);
  __syncthreads();
  for (int i = nbase + tid; i < nend; i += 256) deg[i] = hist[i - nbase];
}

// ------- prefix scan of (deg+1) incl. self-loops (3 kernels, 2048 elems/block) -------
__global__ void k_scan1(const int* __restrict__ deg, int* __restrict__ bsum, int n)
{
  __shared__ int s[256];
  const int t = threadIdx.x;
  const int base = blockIdx.x * 2048 + t * 8;
  int sum = 0;
#pragma unroll
  for (int j = 0; j < 8; j++) { int i = base + j; if (i < n) sum += deg[i] + 1; }
  s[t] = sum; __syncthreads();
  for (int o = 128; o; o >>= 1) { if (t < o) s[t] += s[t + o]; __syncthreads(); }
  if (t == 0) bsum[blockIdx.x] = s[0];
}

__global__ void k_scan2(const int* __restrict__ bsum, int* __restrict__ bofs, int nb)
{
  __shared__ int s[256];
  const int t = threadIdx.x;
  int v = (t < nb) ? bsum[t] : 0;
  s[t] = v; __syncthreads();
  for (int o = 1; o < 256; o <<= 1) {
    int x = (t >= o) ? s[t - o] : 0;
    __syncthreads();
    s[t] += x;
    __syncthreads();
  }
  if (t < nb) bofs[t] = s[t] - v;   // exclusive
}

// scan3 seeds the self-loop edge (elist[off]=i), sets cursor past it, computes dinv
__global__ void k_scan3(const int* __restrict__ deg, const int* __restrict__ bofs,
                        int* __restrict__ offsets, int* __restrict__ cursor,
                        float* __restrict__ dinv, int* __restrict__ elist, int n, int Etot)
{
  __shared__ int s[256];
  const int t = threadIdx.x;
  const int base = blockIdx.x * 2048 + t * 8;
  int loc[8]; int sum = 0;
#pragma unroll
  for (int j = 0; j < 8; j++) { int i = base + j; int d = (i < n) ? deg[i] + 1 : 0; loc[j] = sum; sum += d; }
  const int own = sum;
  s[t] = sum; __syncthreads();
  for (int o = 1; o < 256; o <<= 1) {
    int x = (t >= o) ? s[t - o] : 0;
    __syncthreads();
    s[t] += x;
    __syncthreads();
  }
  const int tbase = bofs[blockIdx.x] + s[t] - own;
#pragma unroll
  for (int j = 0; j < 8; j++) {
    int i = base + j;
    if (i < n) {
      int off = tbase + loc[j];
      offsets[i] = off;
      elist[off] = i;            // self-loop
      cursor[i] = off + 1;
      dinv[i] = rsqrtf((float)(deg[i] + 1));
      if (i == n - 1) offsets[n] = Etot;
    }
  }
}

// per-bucket scatter into CSR; atomics confined to L2-resident windows
__global__ __launch_bounds__(256) void k_scatter2(const uint2* __restrict__ pairs,
                                                  const int* __restrict__ bbase,
                                                  int* __restrict__ cursor, int* __restrict__ elist)
{
  const int b = blockIdx.x;
  const int p0 = bbase[b], p1 = bbase[b + 1];
  for (int p = p0 + threadIdx.x; p < p1; p += 256) {
    const uint2 pr = pairs[p];
    const int pos = atomicAdd(&cursor[pr.x], 1);
    elist[pos] = (int)pr.y;
  }
}

// ------- GCN aggregation: 8 edge-groups x 8 lanes; one uint4 (=full 128B row) per edge -------
// y premultiplied by dinv[src]; final scale by dinv[node].
// FIX vs r5/r6: inner loop is wave-UNIFORM (iters = ceil(m/8)); every lane executes
// every __shfl so the bpermute source lane is always EXEC-active (divergent-shfl on
// CDNA reads undefined data from inactive lanes). Accumulate is predicated on j<m.
__global__ __launch_bounds__(256) void k_agg(const u16* __restrict__ y, const int* __restrict__ offsets,
                                             const int* __restrict__ elist, const float* __restrict__ dinv,
                                             u16* __restrict__ aggx, int n)
{
  const int lane = threadIdx.x & 63;
  const int g = lane >> 3, sub = lane & 7;
  const int wid  = (blockIdx.x * 256 + threadIdx.x) >> 6;
  const int nw   = gridDim.x * 4;
  for (int node = wid; node < n; node += nw) {
    const int s0 = offsets[node], s1 = offsets[node + 1];
    const int deg = s1 - s0;
    float a[8];
#pragma unroll
    for (int t = 0; t < 8; t++) a[t] = 0.f;
    for (int base = 0; base < deg; base += 64) {
      const int m = min(64, deg - base);
      const int ev = (base + lane < deg) ? elist[s0 + base + lane] : 0;
      const int iters = (m + 7) >> 3;        // uniform across the wave
      for (int it = 0; it < iters; it++) {
        const int j = it * 8 + g;            // j <= 63 always
        const int idx = __shfl(ev, j, 64);   // all 64 lanes active here
        if (j < m) {
          const uint4 v = *(const uint4*)(y + (size_t)idx * 64 + sub * 8);
          const u32 w[4] = {v.x, v.y, v.z, v.w};
#pragma unroll
          for (int t = 0; t < 4; t++) {
            a[2 * t]     += b2f((u16)w[t]);
            a[2 * t + 1] += b2f((u16)(w[t] >> 16));
          }
        }
      }
    }
#pragma unroll
    for (int mask = 8; mask <= 32; mask <<= 1) {
#pragma unroll
      for (int t = 0; t < 8; t++) a[t] += __shfl_xor(a[t], mask, 64);
    }
    if (g == 0) {
      const float di = dinv[node];
      u16 o[8];
#pragma unroll
      for (int t = 0; t < 8; t++) o[t] = f2b(a[t] * di);
      *(uint4*)(aggx + (size_t)node * 64 + sub * 8) = *(uint4*)o;
    }
  }
}

// ---------------- BN stats: per-feature sum & sumsq over N rows (round-4 form) ----------------
__global__ __launch_bounds__(256) void k_stats(const u16* __restrict__ h, float* __restrict__ stats, int n)
{
  const int t = threadIdx.x, f = t & 127, half = t >> 7;
  float s = 0.f, q = 0.f;
  for (int r = blockIdx.x * 2 + half; r < n; r += gridDim.x * 2) {
    float v = b2f(h[(size_t)r * 128 + f]);
    s += v; q += v * v;
  }
  __shared__ float red[512];
  red[t] = s; red[256 + t] = q; __syncthreads();
  if (t < 128) {
    atomicAdd(&stats[f],       red[t] + red[t + 128]);
    atomicAdd(&stats[128 + f], red[256 + t] + red[256 + t + 128]);
  }
}

// ---- graph boundaries from sorted batch: gofs[g] = #nodes with batch < g ----
__global__ void k_bounds(const int* __restrict__ batch, int* __restrict__ gofs, int n, int B)
{
  int i = blockIdx.x * 256 + threadIdx.x;
  if (i == 0) { for (int g = 0; g <= batch[0]; g++) gofs[g] = 0; }
  if (i == n - 1) { for (int g = batch[n - 1] + 1; g <= B; g++) gofs[g] = n; }
  if (i < n - 1) {
    const int b0 = batch[i], b1 = batch[i + 1];
    for (int g = b0 + 1; g <= b1; g++) gofs[g] = i + 1;
  }
}

// ---- fold BN0 into W1 (16 blocks x 8 k-rows): W1p = diag(a0)W1 hi/lo T, b1p = c0@W1+b1 ----
__global__ void k_prep1(const float* __restrict__ stats0, const float* __restrict__ W1,
                        const float* __restrict__ b1, const float* __restrict__ g0,
                        const float* __restrict__ be0, u16* __restrict__ W1hiT,
                        u16* __restrict__ W1loT, float* __restrict__ b1p, float n)
{
  __shared__ float A[8], Csh[8];
  const int t = threadIdx.x;  // 128 threads
  if (t < 8) {
    const int k = blockIdx.x * 8 + t;
    const float mu = stats0[k] / n;
    const float var = fmaxf(stats0[128 + k] / n - mu * mu, 0.f);
    const float a = g0[k] * rsqrtf(var + EPS);
    A[t] = a; Csh[t] = be0[k] - mu * a;
  }
  __syncthreads();
  float acc = (blockIdx.x == 0) ? b1[t] : 0.f;
#pragma unroll
  for (int kk = 0; kk < 8; kk++) {
    const int k = blockIdx.x * 8 + kk;
    const float w0 = W1[k * 128 + t];
    acc += Csh[kk] * w0;
    const float w = A[kk] * w0;
    const u16 h = f2b(w);
    W1hiT[t * 128 + k] = h;
    W1loT[t * 128 + k] = f2b(w - b2f(h));
  }
  atomicAdd(&b1p[t], acc);
}

// ---------------- fold BN1/BN2 + concat + W3 into w1f,w2f,constS ----------------
__global__ void k_prep2(const float* __restrict__ stats1, const float* __restrict__ stats2,
                        const float* __restrict__ g1, const float* __restrict__ be1,
                        const float* __restrict__ g2, const float* __restrict__ be2,
                        const float* __restrict__ W3, const float* __restrict__ b3,
                        float* __restrict__ w1f, float* __restrict__ w2f,
                        float* __restrict__ constS, float n)
{
  __shared__ float red[256];
  const int t = threadIdx.x;  // 256 threads
  float c, wv;
  if (t < 128) {
    const float mu = stats1[t] / n;
    const float var = fmaxf(stats1[128 + t] / n - mu * mu, 0.f);
    const float a = g1[t] * rsqrtf(var + EPS);
    c = be1[t] - mu * a;
    wv = W3[t];
    w1f[t] = a * wv;
  } else {
    const int f = t - 128;
    const float mu = stats2[f] / n;
    const float var = fmaxf(stats2[128 + f] / n - mu * mu, 0.f);
    const float a = g2[f] * rsqrtf(var + EPS);
    c = be2[f] - mu * a;
    wv = W3[t];
    w2f[f] = a * wv;
  }
  red[t] = c * wv; __syncthreads();
  for (int o = 128; o; o >>= 1) { if (t < o) red[t] += red[t + o]; __syncthreads(); }
  if (t == 0) { constS[0] = red[0] + b3[0]; constS[1] = b3[0]; }
}

// ---------------- per-node dot: s[n] = h1[n].w1f + h2[n].w2f ----------------
__global__ __launch_bounds__(256) void k_dot(const u16* __restrict__ h1, const u16* __restrict__ h2,
                                             const float* __restrict__ w1f, const float* __restrict__ w2f,
                                             float* __restrict__ s, int n)
{
  const int lane = threadIdx.x & 63;
  const int wid  = (blockIdx.x * 256 + threadIdx.x) >> 6;
  const int nw   = gridDim.x * 4;
  const float a0 = w1f[2 * lane], a1 = w1f[2 * lane + 1];
  const float c0 = w2f[2 * lane], c1 = w2f[2 * lane + 1];
  for (int node = wid; node < n; node += nw) {
    const u32 v1 = *(const u32*)(h1 + (size_t)node * 128 + 2 * lane);
    const u32 v2 = *(const u32*)(h2 + (size_t)node * 128 + 2 * lane);
    float d = b2f((u16)v1) * a0 + b2f((u16)(v1 >> 16)) * a1
            + b2f((u16)v2) * c0 + b2f((u16)(v2 >> 16)) * c1;
#pragma unroll
    for (int o = 1; o < 64; o <<= 1) d += __shfl_xor(d, o, 64);
    if (lane == 0) s[node] = d;
  }
}

// ---------------- per-graph mean + head ----------------
__global__ void k_out(const float* __restrict__ s, const int* __restrict__ gofs,
                      const float* __restrict__ constS, float* __restrict__ out, int B)
{
  const int lane = threadIdx.x & 63;
  const int g = (blockIdx.x * 256 + threadIdx.x) >> 6;
  if (g >= B) return;
  const int st = gofs[g], en = gofs[g + 1], c = en - st;
  float acc = 0.f;
  for (int i = st + lane; i < en; i += 64) acc += s[i];
#pragma unroll
  for (int o = 1; o < 64; o <<= 1) acc += __shfl_xor(acc, o, 64);
  if (lane == 0) out[g] = (c > 0) ? acc / (float)c + constS[0] : constS[1];
}

extern "C" void kernel_launch(void* const* d_in, const int* in_sizes, int n_in,
                              void* d_out, int out_size, void* d_ws, size_t ws_size,
                              hipStream_t stream)
{
  const float* x    = (const float*)d_in[0];
  const float* act  = (const float*)d_in[1];
  const float* Wg   = (const float*)d_in[2];
  const float* bg   = (const float*)d_in[3];
  const float* g0   = (const float*)d_in[4];
  const float* be0  = (const float*)d_in[5];
  const float* W1   = (const float*)d_in[6];
  const float* b1   = (const float*)d_in[7];
  const float* g1   = (const float*)d_in[8];
  const float* be1  = (const float*)d_in[9];
  const float* W2   = (const float*)d_in[10];
  const float* b2   = (const float*)d_in[11];
  const float* g2   = (const float*)d_in[12];
  const float* be2  = (const float*)d_in[13];
  const float* W3   = (const float*)d_in[14];
  const float* b3   = (const float*)d_in[15];
  const int* eidx   = (const int*)d_in[16];
  const int* batch  = (const int*)d_in[17];

  const int N = in_sizes[17];          // 200000
  const int E = in_sizes[16] / 2;      // 1600000
  const int B = out_size;              // 1000
  const int* src = eidx;
  const int* dst = eidx + E;
  const int NB = (N + (1 << BSHIFT) - 1) >> BSHIFT;   // ~391 buckets

  char* ws = (char*)d_ws;
  size_t off = 0;
  auto alloc = [&](size_t bytes) -> char* {
    off = (off + 255) & ~(size_t)255;
    char* p = ws + off; off += bytes; return p;
  };

  u16* bufA = (u16*)alloc((size_t)N * 128 * 2);   // h0, later h2
  u16* h1   = (u16*)alloc((size_t)N * 128 * 2);
  u16* xb   = (u16*)alloc((size_t)N * 64 * 2);    // y (premult bf16 x), later s (f32 N)
  u16* aggx = (u16*)alloc((size_t)N * 64 * 2);

  const size_t zbytes = (768 + 128 + 2 * (size_t)NB) * 4;
  char* zbase   = alloc(zbytes);
  float* stats0 = (float*)zbase;
  float* stats1 = stats0 + 256;
  float* stats2 = stats1 + 256;
  float* b1p    = stats2 + 256;
  int*   btot   = (int*)(b1p + 128);
  int*   bcur   = btot + NB;

  int*   deg     = (int*)alloc((size_t)N * 4);
  int*   offsets = (int*)alloc((size_t)(N + 1) * 4);
  int*   cursor  = (int*)alloc((size_t)N * 4);
  float* dinv    = (float*)alloc((size_t)N * 4);
  int*   elist   = (int*)alloc((size_t)(E + N) * 4);
  uint2* pairs   = (uint2*)alloc((size_t)E * 8);
  int*   bbase   = (int*)alloc((size_t)(NB + 1) * 4);
  int*   bsum    = (int*)alloc(256 * 4);
  int*   bofs    = (int*)alloc(256 * 4);
  int*   gofs    = (int*)alloc((size_t)(B + 1) * 4);
  u16*   WghiT   = (u16*)alloc(128 * 64 * 2);
  u16*   WgloT   = (u16*)alloc(128 * 64 * 2);
  u16*   W1hiT   = (u16*)alloc(128 * 128 * 2);
  u16*   W1loT   = (u16*)alloc(128 * 128 * 2);
  u16*   W2hiT   = (u16*)alloc(128 * 32 * 2);
  u16*   W2loT   = (u16*)alloc(128 * 32 * 2);
  float* w1f     = (float*)alloc(128 * 4);
  float* w2f     = (float*)alloc(128 * 4);
  float* constS  = (float*)alloc(2 * 4);

  u16* h0 = bufA;
  u16* h2 = bufA;            // h0 dead after GEMM-h1 which precedes GEMM-h2
  float* s = (float*)xb;     // y dead after k_agg

  hipMemsetAsync(zbase, 0, zbytes, stream);

  const int nscan = (N + 2047) / 2048;

  // weight prep
  k_splitall<<<48, 256, 0, stream>>>(Wg, W2, WghiT, WgloT, W2hiT, W2loT);
  // binned edge partition + CSR build (round-4 verified chain)
  k_bincnt<<<256, 256, NB * 4, stream>>>(dst, btot, E, NB);
  k_exscan<<<1, 256, 0, stream>>>(btot, bbase, NB);
  k_bin<<<256, 256, 2 * NB * 4, stream>>>(src, dst, bbase, bcur, pairs, E, NB);
  k_degloc<<<NB, 256, 0, stream>>>(pairs, bbase, deg, N);
  k_scan1<<<nscan, 256, 0, stream>>>(deg, bsum, N);
  k_scan2<<<1, 256, 0, stream>>>(bsum, bofs, nscan);
  k_scan3<<<nscan, 256, 0, stream>>>(deg, bofs, offsets, cursor, dinv, elist, N, E + N);
  k_scatter2<<<NB, 256, 0, stream>>>(pairs, bbase, cursor, elist);
  // y = bf16(x * dinv), aggregate, GEMM -> h0, stats0
  k_cast<<<(N * 64 / 8 + 255) / 256, 256, 0, stream>>>(x, dinv, xb, N * 64);
  k_agg<<<2048, 256, 0, stream>>>(xb, offsets, elist, dinv, aggx, N);
  k_gemm<64, true, true, false><<<1024, 256, 0, stream>>>(aggx, WghiT, WgloT, bg, h0, N);
  k_stats<<<1024, 256, 0, stream>>>(h0, stats0, N);
  k_bounds<<<(N + 255) / 256, 256, 0, stream>>>(batch, gofs, N, B);
  // fold BN0 into W1; h1 = relu(h0n @ W1 + b1); stats1
  k_prep1<<<16, 128, 0, stream>>>(stats0, W1, b1, g0, be0, W1hiT, W1loT, b1p, (float)N);
  k_gemm<128, true, true, false><<<1024, 256, 0, stream>>>(h0, W1hiT, W1loT, b1p, h1, N);
  k_stats<<<1024, 256, 0, stream>>>(h1, stats1, N);
  // h2 = relu(action @ W2 + b2); stats2
  k_gemm<32, true, true, true><<<1024, 256, 0, stream>>>(act, W2hiT, W2loT, b2, h2, N);
  k_stats<<<1024, 256, 0, stream>>>(h2, stats2, N);
  // fold BN1/BN2 + W3; pooled dot; output
  k_prep2<<<1, 256, 0, stream>>>(stats1, stats2, g1, be1, g2, be2, W3, b3, w1f, w2f, constS, (float)N);
  k_dot<<<1024, 256, 0, stream>>>(h1, h2, w1f, w2f, s, N);
  k_out<<<(B * 64 + 255) / 256, 256, 0, stream>>>(s, gofs, constS, (float*)d_out, B);
}

// Round 8
// 485.674 us; speedup vs baseline: 1.9037x; 1.2228x over previous
//
#include <hip/hip_runtime.h>

typedef unsigned short u16;
typedef unsigned int   u32;
typedef __bf16 bf16x8 __attribute__((ext_vector_type(8)));
typedef float  f32x4  __attribute__((ext_vector_type(4)));

#define EPS 1e-5f
#define BSHIFT 9               // 512 node ids per bucket

__device__ __forceinline__ float b2f(u16 u){ union{u32 i; float f;} v; v.i=((u32)u)<<16; return v.f; }
__device__ __forceinline__ u16 f2b(float f){
  u32 x = __float_as_uint(f);
  u32 r = x + 0x7fffu + ((x>>16)&1u);   // round-to-nearest-even
  return (u16)(r>>16);
}

// ---- GEMM: C[M,128] = act(A[M,K] @ (Bhi+Blo) + bias), fused per-feature BN stats ----
// B pre-split hi/lo bf16, pre-transposed [128,K]; staged once into LDS with XOR
// swizzle. Wave computes 16 rows x 128 cols via 16x16x32 MFMA, hi+lo weights.
// Epilogue accumulates sum/sumsq of post-activation values into stats[256].
template<int K, bool RELU, bool HASBIAS, bool AF32>
__global__ __launch_bounds__(256) void k_gemm(const void* __restrict__ Av,
                                              const u16* __restrict__ BhiT,
                                              const u16* __restrict__ BloT,
                                              const float* __restrict__ bias,
                                              u16* __restrict__ C,
                                              float* __restrict__ stats, int M)
{
  constexpr int KM = K / 8;                 // 8-elem blocks per row
  __shared__ u16 lds[2 * 128 * K];          // [hi|lo][128 cols][K swizzled]
  __shared__ float sred[128], qred[128];
  const int tid = threadIdx.x;
  for (int i = tid; i < 128 * KM; i += 256) {
    const int n = i / KM, kb = i % KM;
    const int kb2 = kb ^ (n & (KM - 1));
    *(uint4*)(&lds[(n * KM + kb2) * 8])           = *(const uint4*)(BhiT + i * 8);
    *(uint4*)(&lds[128 * K + (n * KM + kb2) * 8]) = *(const uint4*)(BloT + i * 8);
  }
  if (tid < 128) { sred[tid] = 0.f; qred[tid] = 0.f; }
  __syncthreads();
  const int wid = tid >> 6, lane = tid & 63, q = lane >> 4, r16 = lane & 15;
  const int ntiles = M >> 6;                // M divisible by 64 (200000 = 3125*64)
  float ls[8], lq[8];
#pragma unroll
  for (int nb = 0; nb < 8; nb++) { ls[nb] = 0.f; lq[nb] = 0.f; }
  for (int tile = blockIdx.x; tile < ntiles; tile += gridDim.x) {
    const int arow = (tile << 6) + (wid << 4) + r16;
    bf16x8 av[K / 32];
    if (AF32) {
      const float* Af = (const float*)Av + (size_t)arow * K + q * 8;
#pragma unroll
      for (int kk = 0; kk < K / 32; kk++) {
        f32x4 x0 = *(const f32x4*)(Af + kk * 32);
        f32x4 x1 = *(const f32x4*)(Af + kk * 32 + 4);
#pragma unroll
        for (int j = 0; j < 4; j++) { av[kk][j] = (__bf16)x0[j]; av[kk][4 + j] = (__bf16)x1[j]; }
      }
    } else {
      const u16* Ab = (const u16*)Av + (size_t)arow * K + q * 8;
#pragma unroll
      for (int kk = 0; kk < K / 32; kk++) av[kk] = *(const bf16x8*)(Ab + kk * 32);
    }
    f32x4 acc[8];
#pragma unroll
    for (int nb = 0; nb < 8; nb++) acc[nb] = (f32x4){0.f, 0.f, 0.f, 0.f};
#pragma unroll
    for (int kk = 0; kk < K / 32; kk++) {
#pragma unroll
      for (int nb = 0; nb < 8; nb++) {
        const int n = nb * 16 + r16;
        const int kb2 = (kk * 4 + q) ^ (n & (KM - 1));
        const bf16x8 bh = *(const bf16x8*)(&lds[(n * KM + kb2) * 8]);
        const bf16x8 bl = *(const bf16x8*)(&lds[128 * K + (n * KM + kb2) * 8]);
        acc[nb] = __builtin_amdgcn_mfma_f32_16x16x32_bf16(av[kk], bh, acc[nb], 0, 0, 0);
        acc[nb] = __builtin_amdgcn_mfma_f32_16x16x32_bf16(av[kk], bl, acc[nb], 0, 0, 0);
      }
    }
    const int rbase = (tile << 6) + (wid << 4) + (q << 2);
#pragma unroll
    for (int nb = 0; nb < 8; nb++) {
      const int col = nb * 16 + r16;
      const float bv = HASBIAS ? bias[col] : 0.f;
#pragma unroll
      for (int r = 0; r < 4; r++) {
        float v = acc[nb][r] + bv;
        if (RELU) v = fmaxf(v, 0.f);
        ls[nb] += v; lq[nb] += v * v;
        C[(size_t)(rbase + r) * 128 + col] = f2b(v);
      }
    }
  }
#pragma unroll
  for (int nb = 0; nb < 8; nb++) {
    atomicAdd(&sred[nb * 16 + r16], ls[nb]);
    atomicAdd(&qred[nb * 16 + r16], lq[nb]);
  }
  __syncthreads();
  if (tid < 128) {
    atomicAdd(&stats[tid], sred[tid]);
    atomicAdd(&stats[128 + tid], qred[tid]);
  }
}

// ---- split fp32 Wg[64,128] and W2[32,128] -> hi/lo bf16 transposed, one launch ----
__global__ void k_splitall(const float* __restrict__ Wg, const float* __restrict__ W2,
                           u16* __restrict__ WghiT, u16* __restrict__ WgloT,
                           u16* __restrict__ W2hiT, u16* __restrict__ W2loT)
{
  int i = blockIdx.x * 256 + threadIdx.x;
  if (i < 64 * 128) {
    int k = i >> 7, n = i & 127;
    float w = Wg[i]; u16 h = f2b(w);
    WghiT[n * 64 + k] = h; WgloT[n * 64 + k] = f2b(w - b2f(h));
  } else if (i < 64 * 128 + 32 * 128) {
    int j = i - 64 * 128;
    int k = j >> 7, n = j & 127;
    float w = W2[j]; u16 h = f2b(w);
    W2hiT[n * 32 + k] = h; W2loT[n * 32 + k] = f2b(w - b2f(h));
  }
}

// ---------------- cast + premultiply: y[i][f] = bf16(x[i][f] * dinv[i]) ----------------
__global__ void k_cast(const float* __restrict__ x, const float* __restrict__ dinv,
                       u16* __restrict__ y, int n)
{
  int i = (blockIdx.x * 256 + threadIdx.x) * 8;
  if (i < n) {
    const float d = dinv[i >> 6];
    f32x4 a = *(const f32x4*)(x + i);
    f32x4 b = *(const f32x4*)(x + i + 4);
    u16 o[8];
#pragma unroll
    for (int j = 0; j < 4; j++) { o[j] = f2b(a[j] * d); o[4 + j] = f2b(b[j] * d); }
    *(uint4*)(y + i) = *(uint4*)o;
  }
}

// ========== binned edge partition ==========
__global__ __launch_bounds__(256) void k_bincnt(const int* __restrict__ dst, int* __restrict__ btot,
                                                int E, int NB)
{
  extern __shared__ int hist[];
  const int tid = threadIdx.x;
  for (int i = tid; i < NB; i += 256) hist[i] = 0;
  __syncthreads();
  const int chunk = (E + gridDim.x - 1) / gridDim.x;
  const int start = blockIdx.x * chunk;
  const int end = min(start + chunk, E);
  for (int e = start + tid; e < end; e += 256) atomicAdd(&hist[((u32)dst[e]) >> BSHIFT], 1);
  __syncthreads();
  for (int i = tid; i < NB; i += 256) if (hist[i]) atomicAdd(&btot[i], hist[i]);
}

// single-block exclusive scan; out[0..n-1] = exclusive, out[n] = total
__global__ void k_exscan(const int* __restrict__ in, int* __restrict__ out, int n)
{
  __shared__ int s[256];
  const int t = threadIdx.x;
  const int per = (n + 255) / 256;
  const int base = t * per;
  int loc[8]; int sum = 0;
  for (int j = 0; j < per; j++) { int v = (base + j < n) ? in[base + j] : 0; loc[j] = sum; sum += v; }
  s[t] = sum; __syncthreads();
  for (int o = 1; o < 256; o <<= 1) {
    int x = (t >= o) ? s[t - o] : 0;
    __syncthreads();
    s[t] += x;
    __syncthreads();
  }
  const int ex = s[t] - sum;
  for (int j = 0; j < per; j++) if (base + j < n) out[base + j] = ex + loc[j];
  if (t == 255) out[n] = s[255];
}

// re-read edges, reserve per-(block,bucket) ranges, stream (dst,src) pairs
__global__ __launch_bounds__(256) void k_bin(const int* __restrict__ src, const int* __restrict__ dst,
                                             const int* __restrict__ bbase, int* __restrict__ bcur,
                                             uint2* __restrict__ pairs, int E, int NB)
{
  extern __shared__ int lds[];
  int* hist = lds; int* wbase = lds + NB;
  const int tid = threadIdx.x;
  for (int i = tid; i < NB; i += 256) hist[i] = 0;
  __syncthreads();
  const int chunk = (E + gridDim.x - 1) / gridDim.x;
  const int start = blockIdx.x * chunk;
  const int end = min(start + chunk, E);
  for (int e = start + tid; e < end; e += 256) atomicAdd(&hist[((u32)dst[e]) >> BSHIFT], 1);
  __syncthreads();
  for (int i = tid; i < NB; i += 256) {
    int c = hist[i];
    wbase[i] = c ? bbase[i] + atomicAdd(&bcur[i], c) : 0;
    hist[i] = 0;
  }
  __syncthreads();
  for (int e = start + tid; e < end; e += 256) {
    const int d = dst[e];
    const int b = ((u32)d) >> BSHIFT;
    const int o = atomicAdd(&hist[b], 1);
    pairs[wbase[b] + o] = make_uint2((u32)d, (u32)src[e]);
  }
}

// ---- per-bucket: degree hist -> LDS scan -> offsets/dinv/self-loop -> scatter ----
// Bucket owns nodes [b*512, b*512+512); LDS cursors, zero global atomics.
// Global CSR offset of node i: (edges with dst<i) + (self-loops of nodes<i) = p0+ex+i.
__global__ __launch_bounds__(256) void k_bucket(const uint2* __restrict__ pairs,
                                                const int* __restrict__ bbase,
                                                int* __restrict__ offsets, float* __restrict__ dinv,
                                                int* __restrict__ elist, int N, int NB, int Etot)
{
  __shared__ int hist[512];
  __shared__ int scan[256];
  __shared__ int lcur[512];
  const int b = blockIdx.x, t = threadIdx.x;
  const int nbase = b << BSHIFT;
  const int nn = min(1 << BSHIFT, N - nbase);
  hist[t] = 0; hist[256 + t] = 0;
  __syncthreads();
  const int p0 = bbase[b], p1 = bbase[b + 1];
  for (int p = p0 + t; p < p1; p += 256) atomicAdd(&hist[pairs[p].x - nbase], 1);
  __syncthreads();
  const int h0 = hist[2 * t], h1 = hist[2 * t + 1];
  const int psum = h0 + h1;
  scan[t] = psum; __syncthreads();
  for (int o = 1; o < 256; o <<= 1) {
    int x = (t >= o) ? scan[t - o] : 0;
    __syncthreads();
    scan[t] += x;
    __syncthreads();
  }
  const int ex = scan[t] - psum;   // edges in this bucket before node 2t
  const int li0 = 2 * t, li1 = 2 * t + 1;
  if (li0 < nn) {
    const int i = nbase + li0;
    const int off = p0 + ex + i;
    offsets[i] = off; elist[off] = i; lcur[li0] = off + 1;
    dinv[i] = rsqrtf((float)(h0 + 1));
  }
  if (li1 < nn) {
    const int i = nbase + li1;
    const int off = p0 + ex + h0 + i;
    offsets[i] = off; elist[off] = i; lcur[li1] = off + 1;
    dinv[i] = rsqrtf((float)(h1 + 1));
  }
  if (b == NB - 1 && t == 0) offsets[N] = Etot;
  __syncthreads();
  for (int p = p0 + t; p < p1; p += 256) {
    const uint2 pr = pairs[p];
    const int pos = atomicAdd(&lcur[pr.x - nbase], 1);
    elist[pos] = (int)pr.y;
  }
}

// ------- GCN aggregation: 8 edge-groups x 8 lanes; one uint4 (=full 128B row) per edge -------
// y premultiplied by dinv[src]; final scale by dinv[node]. Wave-UNIFORM shfl loop
// (divergent __shfl on CDNA reads undefined data from EXEC-inactive lanes — r5/r6 bug).
__global__ __launch_bounds__(256) void k_agg(const u16* __restrict__ y, const int* __restrict__ offsets,
                                             const int* __restrict__ elist, const float* __restrict__ dinv,
                                             u16* __restrict__ aggx, int n)
{
  const int lane = threadIdx.x & 63;
  const int g = lane >> 3, sub = lane & 7;
  const int wid  = (blockIdx.x * 256 + threadIdx.x) >> 6;
  const int nw   = gridDim.x * 4;
  for (int node = wid; node < n; node += nw) {
    const int s0 = offsets[node], s1 = offsets[node + 1];
    const int deg = s1 - s0;
    float a[8];
#pragma unroll
    for (int t = 0; t < 8; t++) a[t] = 0.f;
    for (int base = 0; base < deg; base += 64) {
      const int m = min(64, deg - base);
      const int ev = (base + lane < deg) ? elist[s0 + base + lane] : 0;
      const int iters = (m + 7) >> 3;        // uniform across the wave
      for (int it = 0; it < iters; it++) {
        const int j = it * 8 + g;            // j <= 63 always
        const int idx = __shfl(ev, j, 64);   // all 64 lanes active here
        if (j < m) {
          const uint4 v = *(const uint4*)(y + (size_t)idx * 64 + sub * 8);
          const u32 w[4] = {v.x, v.y, v.z, v.w};
#pragma unroll
          for (int t = 0; t < 4; t++) {
            a[2 * t]     += b2f((u16)w[t]);
            a[2 * t + 1] += b2f((u16)(w[t] >> 16));
          }
        }
      }
    }
#pragma unroll
    for (int mask = 8; mask <= 32; mask <<= 1) {
#pragma unroll
      for (int t = 0; t < 8; t++) a[t] += __shfl_xor(a[t], mask, 64);
    }
    if (g == 0) {
      const float di = dinv[node];
      u16 o[8];
#pragma unroll
      for (int t = 0; t < 8; t++) o[t] = f2b(a[t] * di);
      *(uint4*)(aggx + (size_t)node * 64 + sub * 8) = *(uint4*)o;
    }
  }
}

// ---- graph boundaries from sorted batch: gofs[g] = #nodes with batch < g ----
__global__ void k_bounds(const int* __restrict__ batch, int* __restrict__ gofs, int n, int B)
{
  int i = blockIdx.x * 256 + threadIdx.x;
  if (i == 0) { for (int g = 0; g <= batch[0]; g++) gofs[g] = 0; }
  if (i == n - 1) { for (int g = batch[n - 1] + 1; g <= B; g++) gofs[g] = n; }
  if (i < n - 1) {
    const int b0 = batch[i], b1 = batch[i + 1];
    for (int g = b0 + 1; g <= b1; g++) gofs[g] = i + 1;
  }
}

// ---- fold BN0 into W1 (16 blocks x 8 k-rows): W1p = diag(a0)W1 hi/lo T, b1p = c0@W1+b1 ----
__global__ void k_prep1(const float* __restrict__ stats0, const float* __restrict__ W1,
                        const float* __restrict__ b1, const float* __restrict__ g0,
                        const float* __restrict__ be0, u16* __restrict__ W1hiT,
                        u16* __restrict__ W1loT, float* __restrict__ b1p, float n)
{
  __shared__ float A[8], Csh[8];
  const int t = threadIdx.x;  // 128 threads
  if (t < 8) {
    const int k = blockIdx.x * 8 + t;
    const float mu = stats0[k] / n;
    const float var = fmaxf(stats0[128 + k] / n - mu * mu, 0.f);
    const float a = g0[k] * rsqrtf(var + EPS);
    A[t] = a; Csh[t] = be0[k] - mu * a;
  }
  __syncthreads();
  float acc = (blockIdx.x == 0) ? b1[t] : 0.f;
#pragma unroll
  for (int kk = 0; kk < 8; kk++) {
    const int k = blockIdx.x * 8 + kk;
    const float w0 = W1[k * 128 + t];
    acc += Csh[kk] * w0;
    const float w = A[kk] * w0;
    const u16 h = f2b(w);
    W1hiT[t * 128 + k] = h;
    W1loT[t * 128 + k] = f2b(w - b2f(h));
  }
  atomicAdd(&b1p[t], acc);
}

// ---------------- fold BN1/BN2 + concat + W3 into w1f,w2f,constS ----------------
__global__ void k_prep2(const float* __restrict__ stats1, const float* __restrict__ stats2,
                        const float* __restrict__ g1, const float* __restrict__ be1,
                        const float* __restrict__ g2, const float* __restrict__ be2,
                        const float* __restrict__ W3, const float* __restrict__ b3,
                        float* __restrict__ w1f, float* __restrict__ w2f,
                        float* __restrict__ constS, float n)
{
  __shared__ float red[256];
  const int t = threadIdx.x;  // 256 threads
  float c, wv;
  if (t < 128) {
    const float mu = stats1[t] / n;
    const float var = fmaxf(stats1[128 + t] / n - mu * mu, 0.f);
    const float a = g1[t] * rsqrtf(var + EPS);
    c = be1[t] - mu * a;
    wv = W3[t];
    w1f[t] = a * wv;
  } else {
    const int f = t - 128;
    const float mu = stats2[f] / n;
    const float var = fmaxf(stats2[128 + f] / n - mu * mu, 0.f);
    const float a = g2[f] * rsqrtf(var + EPS);
    c = be2[f] - mu * a;
    wv = W3[t];
    w2f[f] = a * wv;
  }
  red[t] = c * wv; __syncthreads();
  for (int o = 128; o; o >>= 1) { if (t < o) red[t] += red[t + o]; __syncthreads(); }
  if (t == 0) { constS[0] = red[0] + b3[0]; constS[1] = b3[0]; }
}

// ---------------- per-node dot: s[n] = h1[n].w1f + h2[n].w2f ----------------
__global__ __launch_bounds__(256) void k_dot(const u16* __restrict__ h1, const u16* __restrict__ h2,
                                             const float* __restrict__ w1f, const float* __restrict__ w2f,
                                             float* __restrict__ s, int n)
{
  const int lane = threadIdx.x & 63;
  const int wid  = (blockIdx.x * 256 + threadIdx.x) >> 6;
  const int nw   = gridDim.x * 4;
  const float a0 = w1f[2 * lane], a1 = w1f[2 * lane + 1];
  const float c0 = w2f[2 * lane], c1 = w2f[2 * lane + 1];
  for (int node = wid; node < n; node += nw) {
    const u32 v1 = *(const u32*)(h1 + (size_t)node * 128 + 2 * lane);
    const u32 v2 = *(const u32*)(h2 + (size_t)node * 128 + 2 * lane);
    float d = b2f((u16)v1) * a0 + b2f((u16)(v1 >> 16)) * a1
            + b2f((u16)v2) * c0 + b2f((u16)(v2 >> 16)) * c1;
#pragma unroll
    for (int o = 1; o < 64; o <<= 1) d += __shfl_xor(d, o, 64);
    if (lane == 0) s[node] = d;
  }
}

// ---------------- per-graph mean + head ----------------
__global__ void k_out(const float* __restrict__ s, const int* __restrict__ gofs,
                      const float* __restrict__ constS, float* __restrict__ out, int B)
{
  const int lane = threadIdx.x & 63;
  const int g = (blockIdx.x * 256 + threadIdx.x) >> 6;
  if (g >= B) return;
  const int st = gofs[g], en = gofs[g + 1], c = en - st;
  float acc = 0.f;
  for (int i = st + lane; i < en; i += 64) acc += s[i];
#pragma unroll
  for (int o = 1; o < 64; o <<= 1) acc += __shfl_xor(acc, o, 64);
  if (lane == 0) out[g] = (c > 0) ? acc / (float)c + constS[0] : constS[1];
}

extern "C" void kernel_launch(void* const* d_in, const int* in_sizes, int n_in,
                              void* d_out, int out_size, void* d_ws, size_t ws_size,
                              hipStream_t stream)
{
  const float* x    = (const float*)d_in[0];
  const float* act  = (const float*)d_in[1];
  const float* Wg   = (const float*)d_in[2];
  const float* bg   = (const float*)d_in[3];
  const float* g0   = (const float*)d_in[4];
  const float* be0  = (const float*)d_in[5];
  const float* W1   = (const float*)d_in[6];
  const float* b1   = (const float*)d_in[7];
  const float* g1   = (const float*)d_in[8];
  const float* be1  = (const float*)d_in[9];
  const float* W2   = (const float*)d_in[10];
  const float* b2   = (const float*)d_in[11];
  const float* g2   = (const float*)d_in[12];
  const float* be2  = (const float*)d_in[13];
  const float* W3   = (const float*)d_in[14];
  const float* b3   = (const float*)d_in[15];
  const int* eidx   = (const int*)d_in[16];
  const int* batch  = (const int*)d_in[17];

  const int N = in_sizes[17];          // 200000
  const int E = in_sizes[16] / 2;      // 1600000
  const int B = out_size;              // 1000
  const int* src = eidx;
  const int* dst = eidx + E;
  const int NB = (N + (1 << BSHIFT) - 1) >> BSHIFT;   // ~391 buckets

  char* ws = (char*)d_ws;
  size_t off = 0;
  auto alloc = [&](size_t bytes) -> char* {
    off = (off + 255) & ~(size_t)255;
    char* p = ws + off; off += bytes; return p;
  };

  u16* bufA = (u16*)alloc((size_t)N * 128 * 2);   // h0, later h2
  u16* h1   = (u16*)alloc((size_t)N * 128 * 2);
  u16* xb   = (u16*)alloc((size_t)N * 64 * 2);    // y (premult bf16 x), later s (f32 N)
  u16* aggx = (u16*)alloc((size_t)N * 64 * 2);

  const size_t zbytes = (768 + 128 + 2 * (size_t)NB) * 4;
  char* zbase   = alloc(zbytes);
  float* stats0 = (float*)zbase;
  float* stats1 = stats0 + 256;
  float* stats2 = stats1 + 256;
  float* b1p    = stats2 + 256;
  int*   btot   = (int*)(b1p + 128);
  int*   bcur   = btot + NB;

  int*   offsets = (int*)alloc((size_t)(N + 1) * 4);
  float* dinv    = (float*)alloc((size_t)N * 4);
  int*   elist   = (int*)alloc((size_t)(E + N) * 4);
  uint2* pairs   = (uint2*)alloc((size_t)E * 8);
  int*   bbase   = (int*)alloc((size_t)(NB + 1) * 4);
  int*   gofs    = (int*)alloc((size_t)(B + 1) * 4);
  u16*   WghiT   = (u16*)alloc(128 * 64 * 2);
  u16*   WgloT   = (u16*)alloc(128 * 64 * 2);
  u16*   W1hiT   = (u16*)alloc(128 * 128 * 2);
  u16*   W1loT   = (u16*)alloc(128 * 128 * 2);
  u16*   W2hiT   = (u16*)alloc(128 * 32 * 2);
  u16*   W2loT   = (u16*)alloc(128 * 32 * 2);
  float* w1f     = (float*)alloc(128 * 4);
  float* w2f     = (float*)alloc(128 * 4);
  float* constS  = (float*)alloc(2 * 4);

  u16* h0 = bufA;
  u16* h2 = bufA;            // h0 dead after GEMM-h1 which precedes GEMM-h2
  float* s = (float*)xb;     // y dead after k_agg

  hipMemsetAsync(zbase, 0, zbytes, stream);

  // weight prep
  k_splitall<<<48, 256, 0, stream>>>(Wg, W2, WghiT, WgloT, W2hiT, W2loT);
  // binned edge partition -> per-bucket CSR build (offsets, dinv, elist incl self-loops)
  k_bincnt<<<256, 256, NB * 4, stream>>>(dst, btot, E, NB);
  k_exscan<<<1, 256, 0, stream>>>(btot, bbase, NB);
  k_bin<<<256, 256, 2 * NB * 4, stream>>>(src, dst, bbase, bcur, pairs, E, NB);
  k_bucket<<<NB, 256, 0, stream>>>(pairs, bbase, offsets, dinv, elist, N, NB, E + N);
  // y = bf16(x * dinv), aggregate, GEMM (+stats0) -> h0
  k_cast<<<(N * 64 / 8 + 255) / 256, 256, 0, stream>>>(x, dinv, xb, N * 64);
  k_agg<<<2048, 256, 0, stream>>>(xb, offsets, elist, dinv, aggx, N);
  k_gemm<64, true, true, false><<<1024, 256, 0, stream>>>(aggx, WghiT, WgloT, bg, h0, stats0, N);
  k_bounds<<<(N + 255) / 256, 256, 0, stream>>>(batch, gofs, N, B);
  // fold BN0 into W1; h1 = relu(h0n @ W1 + b1) (+stats1)
  k_prep1<<<16, 128, 0, stream>>>(stats0, W1, b1, g0, be0, W1hiT, W1loT, b1p, (float)N);
  k_gemm<128, true, true, false><<<1024, 256, 0, stream>>>(h0, W1hiT, W1loT, b1p, h1, stats1, N);
  // h2 = relu(action @ W2 + b2) (+stats2)
  k_gemm<32, true, true, true><<<1024, 256, 0, stream>>>(act, W2hiT, W2loT, b2, h2, stats2, N);
  // fold BN1/BN2 + W3; pooled dot; output
  k_prep2<<<1, 256, 0, stream>>>(stats1, stats2, g1, be1, g2, be2, W3, b3, w1f, w2f, constS, (float)N);
  k_dot<<<1024, 256, 0, stream>>>(h1, h2, w1f, w2f, s, N);
  k_out<<<(B * 64 + 255) / 256, 256, 0, stream>>>(s, gofs, constS, (float*)d_out, B);
}

// Round 9
// 457.564 us; speedup vs baseline: 2.0207x; 1.0614x over previous
//
#include <hip/hip_runtime.h>

typedef unsigned short u16;
typedef unsigned int   u32;
typedef __bf16 bf16x8 __attribute__((ext_vector_type(8)));
typedef float  f32x4  __attribute__((ext_vector_type(4)));

#define EPS 1e-5f
#define BSHIFT 9               // 512 node ids per bucket

__device__ __forceinline__ float b2f(u16 u){ union{u32 i; float f;} v; v.i=((u32)u)<<16; return v.f; }
__device__ __forceinline__ u16 f2b(float f){
  u32 x = __float_as_uint(f);
  u32 r = x + 0x7fffu + ((x>>16)&1u);   // round-to-nearest-even
  return (u16)(r>>16);
}

// ---- GEMM: C[M,128] = act(A[M,K] @ (Bhi+Blo) + bias), fused per-feature BN stats ----
template<int K, bool RELU, bool HASBIAS, bool AF32>
__global__ __launch_bounds__(256) void k_gemm(const void* __restrict__ Av,
                                              const u16* __restrict__ BhiT,
                                              const u16* __restrict__ BloT,
                                              const float* __restrict__ bias,
                                              u16* __restrict__ C,
                                              float* __restrict__ stats, int M)
{
  constexpr int KM = K / 8;                 // 8-elem blocks per row
  __shared__ u16 lds[2 * 128 * K];          // [hi|lo][128 cols][K swizzled]
  __shared__ float sred[128], qred[128];
  const int tid = threadIdx.x;
  for (int i = tid; i < 128 * KM; i += 256) {
    const int n = i / KM, kb = i % KM;
    const int kb2 = kb ^ (n & (KM - 1));
    *(uint4*)(&lds[(n * KM + kb2) * 8])           = *(const uint4*)(BhiT + i * 8);
    *(uint4*)(&lds[128 * K + (n * KM + kb2) * 8]) = *(const uint4*)(BloT + i * 8);
  }
  if (tid < 128) { sred[tid] = 0.f; qred[tid] = 0.f; }
  __syncthreads();
  const int wid = tid >> 6, lane = tid & 63, q = lane >> 4, r16 = lane & 15;
  const int ntiles = M >> 6;                // M divisible by 64 (200000 = 3125*64)
  float ls[8], lq[8];
#pragma unroll
  for (int nb = 0; nb < 8; nb++) { ls[nb] = 0.f; lq[nb] = 0.f; }
  for (int tile = blockIdx.x; tile < ntiles; tile += gridDim.x) {
    const int arow = (tile << 6) + (wid << 4) + r16;
    bf16x8 av[K / 32];
    if (AF32) {
      const float* Af = (const float*)Av + (size_t)arow * K + q * 8;
#pragma unroll
      for (int kk = 0; kk < K / 32; kk++) {
        f32x4 x0 = *(const f32x4*)(Af + kk * 32);
        f32x4 x1 = *(const f32x4*)(Af + kk * 32 + 4);
#pragma unroll
        for (int j = 0; j < 4; j++) { av[kk][j] = (__bf16)x0[j]; av[kk][4 + j] = (__bf16)x1[j]; }
      }
    } else {
      const u16* Ab = (const u16*)Av + (size_t)arow * K + q * 8;
#pragma unroll
      for (int kk = 0; kk < K / 32; kk++) av[kk] = *(const bf16x8*)(Ab + kk * 32);
    }
    f32x4 acc[8];
#pragma unroll
    for (int nb = 0; nb < 8; nb++) acc[nb] = (f32x4){0.f, 0.f, 0.f, 0.f};
#pragma unroll
    for (int kk = 0; kk < K / 32; kk++) {
#pragma unroll
      for (int nb = 0; nb < 8; nb++) {
        const int n = nb * 16 + r16;
        const int kb2 = (kk * 4 + q) ^ (n & (KM - 1));
        const bf16x8 bh = *(const bf16x8*)(&lds[(n * KM + kb2) * 8]);
        const bf16x8 bl = *(const bf16x8*)(&lds[128 * K + (n * KM + kb2) * 8]);
        acc[nb] = __builtin_amdgcn_mfma_f32_16x16x32_bf16(av[kk], bh, acc[nb], 0, 0, 0);
        acc[nb] = __builtin_amdgcn_mfma_f32_16x16x32_bf16(av[kk], bl, acc[nb], 0, 0, 0);
      }
    }
    const int rbase = (tile << 6) + (wid << 4) + (q << 2);
#pragma unroll
    for (int nb = 0; nb < 8; nb++) {
      const int col = nb * 16 + r16;
      const float bv = HASBIAS ? bias[col] : 0.f;
#pragma unroll
      for (int r = 0; r < 4; r++) {
        float v = acc[nb][r] + bv;
        if (RELU) v = fmaxf(v, 0.f);
        ls[nb] += v; lq[nb] += v * v;
        C[(size_t)(rbase + r) * 128 + col] = f2b(v);
      }
    }
  }
#pragma unroll
  for (int nb = 0; nb < 8; nb++) {
    atomicAdd(&sred[nb * 16 + r16], ls[nb]);
    atomicAdd(&qred[nb * 16 + r16], lq[nb]);
  }
  __syncthreads();
  if (tid < 128) {
    atomicAdd(&stats[tid], sred[tid]);
    atomicAdd(&stats[128 + tid], qred[tid]);
  }
}

// ---- prep0: block 0 zeroes scratch; blocks 1..48 split Wg/W2 hi/lo T; rest: bounds ----
__global__ void k_prep0(const float* __restrict__ Wg, const float* __restrict__ W2,
                        u16* __restrict__ WghiT, u16* __restrict__ WgloT,
                        u16* __restrict__ W2hiT, u16* __restrict__ W2loT,
                        const int* __restrict__ batch, int* __restrict__ gofs,
                        int* __restrict__ zbase, int zwords, int N, int B)
{
  const int bid = blockIdx.x, t = threadIdx.x;
  if (bid == 0) {
    for (int i = t; i < zwords; i += 256) zbase[i] = 0;
  } else if (bid <= 48) {
    const int i = (bid - 1) * 256 + t;
    if (i < 64 * 128) {
      int k = i >> 7, n = i & 127;
      float w = Wg[i]; u16 h = f2b(w);
      WghiT[n * 64 + k] = h; WgloT[n * 64 + k] = f2b(w - b2f(h));
    } else if (i < 64 * 128 + 32 * 128) {
      int j = i - 64 * 128;
      int k = j >> 7, n = j & 127;
      float w = W2[j]; u16 h = f2b(w);
      W2hiT[n * 32 + k] = h; W2loT[n * 32 + k] = f2b(w - b2f(h));
    }
  } else {
    const int i = (bid - 49) * 256 + t;
    if (i == 0) { for (int g = 0; g <= batch[0]; g++) gofs[g] = 0; }
    if (i == N - 1) { for (int g = batch[N - 1] + 1; g <= B; g++) gofs[g] = N; }
    if (i < N - 1) {
      const int b0 = batch[i], b1 = batch[i + 1];
      for (int g = b0 + 1; g <= b1; g++) gofs[g] = i + 1;
    }
  }
}

// ========== binned edge partition ==========
__global__ __launch_bounds__(256) void k_bincnt(const int* __restrict__ dst, int* __restrict__ btot,
                                                int E, int NB)
{
  extern __shared__ int hist[];
  const int tid = threadIdx.x;
  for (int i = tid; i < NB; i += 256) hist[i] = 0;
  __syncthreads();
  const int chunk = (E + gridDim.x - 1) / gridDim.x;
  const int start = blockIdx.x * chunk;
  const int end = min(start + chunk, E);
  for (int e = start + tid; e < end; e += 256) atomicAdd(&hist[((u32)dst[e]) >> BSHIFT], 1);
  __syncthreads();
  for (int i = tid; i < NB; i += 256) if (hist[i]) atomicAdd(&btot[i], hist[i]);
}

// single-block exclusive scan; out[0..n-1] = exclusive, out[n] = total
__global__ void k_exscan(const int* __restrict__ in, int* __restrict__ out, int n)
{
  __shared__ int s[256];
  const int t = threadIdx.x;
  const int per = (n + 255) / 256;
  const int base = t * per;
  int loc[8]; int sum = 0;
  for (int j = 0; j < per; j++) { int v = (base + j < n) ? in[base + j] : 0; loc[j] = sum; sum += v; }
  s[t] = sum; __syncthreads();
  for (int o = 1; o < 256; o <<= 1) {
    int x = (t >= o) ? s[t - o] : 0;
    __syncthreads();
    s[t] += x;
    __syncthreads();
  }
  const int ex = s[t] - sum;
  for (int j = 0; j < per; j++) if (base + j < n) out[base + j] = ex + loc[j];
  if (t == 255) out[n] = s[255];
}

// re-read edges, reserve per-(block,bucket) ranges, stream (dst,src) pairs
__global__ __launch_bounds__(256) void k_bin(const int* __restrict__ src, const int* __restrict__ dst,
                                             const int* __restrict__ bbase, int* __restrict__ bcur,
                                             uint2* __restrict__ pairs, int E, int NB)
{
  extern __shared__ int lds[];
  int* hist = lds; int* wbase = lds + NB;
  const int tid = threadIdx.x;
  for (int i = tid; i < NB; i += 256) hist[i] = 0;
  __syncthreads();
  const int chunk = (E + gridDim.x - 1) / gridDim.x;
  const int start = blockIdx.x * chunk;
  const int end = min(start + chunk, E);
  for (int e = start + tid; e < end; e += 256) atomicAdd(&hist[((u32)dst[e]) >> BSHIFT], 1);
  __syncthreads();
  for (int i = tid; i < NB; i += 256) {
    int c = hist[i];
    wbase[i] = c ? bbase[i] + atomicAdd(&bcur[i], c) : 0;
    hist[i] = 0;
  }
  __syncthreads();
  for (int e = start + tid; e < end; e += 256) {
    const int d = dst[e];
    const int b = ((u32)d) >> BSHIFT;
    const int o = atomicAdd(&hist[b], 1);
    pairs[wbase[b] + o] = make_uint2((u32)d, (u32)src[e]);
  }
}

// ---- per-bucket: degree hist -> LDS scan -> offsets/dinv/self-loop -> scatter ----
// Also fused: y[i] = bf16(x[i] * dinv[i]) for the bucket's own 512 nodes (coalesced).
__global__ __launch_bounds__(256) void k_bucket(const uint2* __restrict__ pairs,
                                                const int* __restrict__ bbase,
                                                const float* __restrict__ x,
                                                int* __restrict__ offsets, float* __restrict__ dinv,
                                                int* __restrict__ elist, u16* __restrict__ y,
                                                int N, int NB, int Etot)
{
  __shared__ int hist[512];
  __shared__ int scan[256];
  __shared__ int lcur[512];
  __shared__ float sdinv[512];
  const int b = blockIdx.x, t = threadIdx.x;
  const int nbase = b << BSHIFT;
  const int nn = min(1 << BSHIFT, N - nbase);
  hist[t] = 0; hist[256 + t] = 0;
  __syncthreads();
  const int p0 = bbase[b], p1 = bbase[b + 1];
  for (int p = p0 + t; p < p1; p += 256) atomicAdd(&hist[pairs[p].x - nbase], 1);
  __syncthreads();
  const int h0 = hist[2 * t], h1 = hist[2 * t + 1];
  const int psum = h0 + h1;
  scan[t] = psum; __syncthreads();
  for (int o = 1; o < 256; o <<= 1) {
    int xx = (t >= o) ? scan[t - o] : 0;
    __syncthreads();
    scan[t] += xx;
    __syncthreads();
  }
  const int ex = scan[t] - psum;   // edges in this bucket before node 2t
  const int li0 = 2 * t, li1 = 2 * t + 1;
  if (li0 < nn) {
    const int i = nbase + li0;
    const int off = p0 + ex + i;
    const float d = rsqrtf((float)(h0 + 1));
    offsets[i] = off; elist[off] = i; lcur[li0] = off + 1;
    dinv[i] = d; sdinv[li0] = d;
  }
  if (li1 < nn) {
    const int i = nbase + li1;
    const int off = p0 + ex + h0 + i;
    const float d = rsqrtf((float)(h1 + 1));
    offsets[i] = off; elist[off] = i; lcur[li1] = off + 1;
    dinv[i] = d; sdinv[li1] = d;
  }
  if (b == NB - 1 && t == 0) offsets[N] = Etot;
  __syncthreads();
  for (int p = p0 + t; p < p1; p += 256) {
    const uint2 pr = pairs[p];
    const int pos = atomicAdd(&lcur[pr.x - nbase], 1);
    elist[pos] = (int)pr.y;
  }
  // fused cast: y rows for this bucket (sdinv visible via the sync above)
  const size_t ebase = (size_t)nbase * 64;
  const int total = nn * 64;
  for (int i = t * 8; i < total; i += 256 * 8) {
    const float d = sdinv[i >> 6];
    f32x4 a = *(const f32x4*)(x + ebase + i);
    f32x4 c = *(const f32x4*)(x + ebase + i + 4);
    u16 o[8];
#pragma unroll
    for (int j = 0; j < 4; j++) { o[j] = f2b(a[j] * d); o[4 + j] = f2b(c[j] * d); }
    *(uint4*)(y + ebase + i) = *(uint4*)o;
  }
}

// ------- GCN aggregation: 2 nodes/wave (half-wave each), 4 groups x 8 lanes per node -------
// y premultiplied by dinv[src]; final scale by dinv[node]. ALL shfls wave-uniform
// (divergent __shfl on CDNA reads undefined data from EXEC-inactive lanes — r5/r6 bug).
__global__ __launch_bounds__(256) void k_agg(const u16* __restrict__ y, const int* __restrict__ offsets,
                                             const int* __restrict__ elist, const float* __restrict__ dinv,
                                             u16* __restrict__ aggx, int n)
{
  const int lane = threadIdx.x & 63;
  const int half = lane >> 5, l32 = lane & 31;
  const int g4 = l32 >> 3, sub = lane & 7;
  const int wid  = (blockIdx.x * 256 + threadIdx.x) >> 6;
  const int nw   = gridDim.x * 4;
  const int npair = (n + 1) >> 1;
  for (int pr = wid; pr < npair; pr += nw) {
    const int node = pr * 2 + half;          // n even -> node < n
    const int s0 = offsets[node], s1 = offsets[node + 1];
    const int mydeg = s1 - s0;
    const int degA = __shfl(mydeg, 0, 64);
    const int degB = __shfl(mydeg, 32, 64);
    const int degmax = max(degA, degB);
    float a[8];
#pragma unroll
    for (int t = 0; t < 8; t++) a[t] = 0.f;
    for (int base = 0; base < degmax; base += 32) {
      const int m = mydeg - base;            // may be <=0 for the finished half
      const int ev = (base + l32 < mydeg) ? elist[s0 + base + l32] : 0;
      const int iters = (min(32, degmax - base) + 3) >> 2;   // wave-uniform
      for (int it = 0; it < iters; it++) {
        const int j = it * 4 + g4;           // 0..31
        const int idx = __shfl(ev, half * 32 + j, 64);   // all lanes active
        if (j < m) {
          const uint4 v = *(const uint4*)(y + (size_t)idx * 64 + sub * 8);
          const u32 w[4] = {v.x, v.y, v.z, v.w};
#pragma unroll
          for (int t = 0; t < 4; t++) {
            a[2 * t]     += b2f((u16)w[t]);
            a[2 * t + 1] += b2f((u16)(w[t] >> 16));
          }
        }
      }
    }
#pragma unroll
    for (int t = 0; t < 8; t++) {
      a[t] += __shfl_xor(a[t], 8, 64);
      a[t] += __shfl_xor(a[t], 16, 64);
    }
    if (g4 == 0) {
      const float di = dinv[node];
      u16 o[8];
#pragma unroll
      for (int t = 0; t < 8; t++) o[t] = f2b(a[t] * di);
      *(uint4*)(aggx + (size_t)node * 64 + sub * 8) = *(uint4*)o;
    }
  }
}

// ---- fold BN0 into W1 (16 blocks x 8 k-rows): W1p = diag(a0)W1 hi/lo T, b1p = c0@W1+b1 ----
__global__ void k_prep1(const float* __restrict__ stats0, const float* __restrict__ W1,
                        const float* __restrict__ b1, const float* __restrict__ g0,
                        const float* __restrict__ be0, u16* __restrict__ W1hiT,
                        u16* __restrict__ W1loT, float* __restrict__ b1p, float n)
{
  __shared__ float A[8], Csh[8];
  const int t = threadIdx.x;  // 128 threads
  if (t < 8) {
    const int k = blockIdx.x * 8 + t;
    const float mu = stats0[k] / n;
    const float var = fmaxf(stats0[128 + k] / n - mu * mu, 0.f);
    const float a = g0[k] * rsqrtf(var + EPS);
    A[t] = a; Csh[t] = be0[k] - mu * a;
  }
  __syncthreads();
  float acc = (blockIdx.x == 0) ? b1[t] : 0.f;
#pragma unroll
  for (int kk = 0; kk < 8; kk++) {
    const int k = blockIdx.x * 8 + kk;
    const float w0 = W1[k * 128 + t];
    acc += Csh[kk] * w0;
    const float w = A[kk] * w0;
    const u16 h = f2b(w);
    W1hiT[t * 128 + k] = h;
    W1loT[t * 128 + k] = f2b(w - b2f(h));
  }
  atomicAdd(&b1p[t], acc);
}

// ---------------- fold BN1/BN2 + concat + W3 into w1f,w2f,constS ----------------
__global__ void k_prep2(const float* __restrict__ stats1, const float* __restrict__ stats2,
                        const float* __restrict__ g1, const float* __restrict__ be1,
                        const float* __restrict__ g2, const float* __restrict__ be2,
                        const float* __restrict__ W3, const float* __restrict__ b3,
                        float* __restrict__ w1f, float* __restrict__ w2f,
                        float* __restrict__ constS, float n)
{
  __shared__ float red[256];
  const int t = threadIdx.x;  // 256 threads
  float c, wv;
  if (t < 128) {
    const float mu = stats1[t] / n;
    const float var = fmaxf(stats1[128 + t] / n - mu * mu, 0.f);
    const float a = g1[t] * rsqrtf(var + EPS);
    c = be1[t] - mu * a;
    wv = W3[t];
    w1f[t] = a * wv;
  } else {
    const int f = t - 128;
    const float mu = stats2[f] / n;
    const float var = fmaxf(stats2[128 + f] / n - mu * mu, 0.f);
    const float a = g2[f] * rsqrtf(var + EPS);
    c = be2[f] - mu * a;
    wv = W3[t];
    w2f[f] = a * wv;
  }
  red[t] = c * wv; __syncthreads();
  for (int o = 128; o; o >>= 1) { if (t < o) red[t] += red[t + o]; __syncthreads(); }
  if (t == 0) { constS[0] = red[0] + b3[0]; constS[1] = b3[0]; }
}

// ---------------- per-node dot: s[n] = h1[n].w1f + h2[n].w2f ----------------
__global__ __launch_bounds__(256) void k_dot(const u16* __restrict__ h1, const u16* __restrict__ h2,
                                             const float* __restrict__ w1f, const float* __restrict__ w2f,
                                             float* __restrict__ s, int n)
{
  const int lane = threadIdx.x & 63;
  const int wid  = (blockIdx.x * 256 + threadIdx.x) >> 6;
  const int nw   = gridDim.x * 4;
  const float a0 = w1f[2 * lane], a1 = w1f[2 * lane + 1];
  const float c0 = w2f[2 * lane], c1 = w2f[2 * lane + 1];
  for (int node = wid; node < n; node += nw) {
    const u32 v1 = *(const u32*)(h1 + (size_t)node * 128 + 2 * lane);
    const u32 v2 = *(const u32*)(h2 + (size_t)node * 128 + 2 * lane);
    float d = b2f((u16)v1) * a0 + b2f((u16)(v1 >> 16)) * a1
            + b2f((u16)v2) * c0 + b2f((u16)(v2 >> 16)) * c1;
#pragma unroll
    for (int o = 1; o < 64; o <<= 1) d += __shfl_xor(d, o, 64);
    if (lane == 0) s[node] = d;
  }
}

// ---------------- per-graph mean + head ----------------
__global__ void k_out(const float* __restrict__ s, const int* __restrict__ gofs,
                      const float* __restrict__ constS, float* __restrict__ out, int B)
{
  const int lane = threadIdx.x & 63;
  const int g = (blockIdx.x * 256 + threadIdx.x) >> 6;
  if (g >= B) return;
  const int st = gofs[g], en = gofs[g + 1], c = en - st;
  float acc = 0.f;
  for (int i = st + lane; i < en; i += 64) acc += s[i];
#pragma unroll
  for (int o = 1; o < 64; o <<= 1) acc += __shfl_xor(acc, o, 64);
  if (lane == 0) out[g] = (c > 0) ? acc / (float)c + constS[0] : constS[1];
}

extern "C" void kernel_launch(void* const* d_in, const int* in_sizes, int n_in,
                              void* d_out, int out_size, void* d_ws, size_t ws_size,
                              hipStream_t stream)
{
  const float* x    = (const float*)d_in[0];
  const float* act  = (const float*)d_in[1];
  const float* Wg   = (const float*)d_in[2];
  const float* bg   = (const float*)d_in[3];
  const float* g0   = (const float*)d_in[4];
  const float* be0  = (const float*)d_in[5];
  const float* W1   = (const float*)d_in[6];
  const float* b1   = (const float*)d_in[7];
  const float* g1   = (const float*)d_in[8];
  const float* be1  = (const float*)d_in[9];
  const float* W2   = (const float*)d_in[10];
  const float* b2   = (const float*)d_in[11];
  const float* g2   = (const float*)d_in[12];
  const float* be2  = (const float*)d_in[13];
  const float* W3   = (const float*)d_in[14];
  const float* b3   = (const float*)d_in[15];
  const int* eidx   = (const int*)d_in[16];
  const int* batch  = (const int*)d_in[17];

  const int N = in_sizes[17];          // 200000
  const int E = in_sizes[16] / 2;      // 1600000
  const int B = out_size;              // 1000
  const int* src = eidx;
  const int* dst = eidx + E;
  const int NB = (N + (1 << BSHIFT) - 1) >> BSHIFT;   // ~391 buckets

  char* ws = (char*)d_ws;
  size_t off = 0;
  auto alloc = [&](size_t bytes) -> char* {
    off = (off + 255) & ~(size_t)255;
    char* p = ws + off; off += bytes; return p;
  };

  u16* bufA = (u16*)alloc((size_t)N * 128 * 2);   // h0, later h2
  u16* h1   = (u16*)alloc((size_t)N * 128 * 2);
  u16* xb   = (u16*)alloc((size_t)N * 64 * 2);    // y (premult bf16 x), later s (f32 N)
  u16* aggx = (u16*)alloc((size_t)N * 64 * 2);

  const int zwords = 768 + 128 + 2 * NB;
  char* zbase   = alloc((size_t)zwords * 4);
  float* stats0 = (float*)zbase;
  float* stats1 = stats0 + 256;
  float* stats2 = stats1 + 256;
  float* b1p    = stats2 + 256;
  int*   btot   = (int*)(b1p + 128);
  int*   bcur   = btot + NB;

  int*   offsets = (int*)alloc((size_t)(N + 1) * 4);
  float* dinv    = (float*)alloc((size_t)N * 4);
  int*   elist   = (int*)alloc((size_t)(E + N) * 4);
  uint2* pairs   = (uint2*)alloc((size_t)E * 8);
  int*   bbase   = (int*)alloc((size_t)(NB + 1) * 4);
  int*   gofs    = (int*)alloc((size_t)(B + 1) * 4);
  u16*   WghiT   = (u16*)alloc(128 * 64 * 2);
  u16*   WgloT   = (u16*)alloc(128 * 64 * 2);
  u16*   W1hiT   = (u16*)alloc(128 * 128 * 2);
  u16*   W1loT   = (u16*)alloc(128 * 128 * 2);
  u16*   W2hiT   = (u16*)alloc(128 * 32 * 2);
  u16*   W2loT   = (u16*)alloc(128 * 32 * 2);
  float* w1f     = (float*)alloc(128 * 4);
  float* w2f     = (float*)alloc(128 * 4);
  float* constS  = (float*)alloc(2 * 4);

  u16* h0 = bufA;
  u16* h2 = bufA;            // h0 dead after GEMM-h1 which precedes GEMM-h2
  float* s = (float*)xb;     // y dead after k_agg

  // prep0: zero scratch + weight split + graph bounds (one dispatch, replaces memset)
  const int nbounds = (N + 255) / 256;
  k_prep0<<<1 + 48 + nbounds, 256, 0, stream>>>(Wg, W2, WghiT, WgloT, W2hiT, W2loT,
                                                batch, gofs, (int*)zbase, zwords, N, B);
  // binned edge partition -> per-bucket CSR build + fused x->y cast
  k_bincnt<<<256, 256, NB * 4, stream>>>(dst, btot, E, NB);
  k_exscan<<<1, 256, 0, stream>>>(btot, bbase, NB);
  k_bin<<<256, 256, 2 * NB * 4, stream>>>(src, dst, bbase, bcur, pairs, E, NB);
  k_bucket<<<NB, 256, 0, stream>>>(pairs, bbase, x, offsets, dinv, elist, xb, N, NB, E + N);
  // aggregate, GEMM (+stats0) -> h0
  k_agg<<<2048, 256, 0, stream>>>(xb, offsets, elist, dinv, aggx, N);
  k_gemm<64, true, true, false><<<1024, 256, 0, stream>>>(aggx, WghiT, WgloT, bg, h0, stats0, N);
  // fold BN0 into W1; h1 = relu(h0n @ W1 + b1) (+stats1)
  k_prep1<<<16, 128, 0, stream>>>(stats0, W1, b1, g0, be0, W1hiT, W1loT, b1p, (float)N);
  k_gemm<128, true, true, false><<<1024, 256, 0, stream>>>(h0, W1hiT, W1loT, b1p, h1, stats1, N);
  // h2 = relu(action @ W2 + b2) (+stats2)
  k_gemm<32, true, true, true><<<1024, 256, 0, stream>>>(act, W2hiT, W2loT, b2, h2, stats2, N);
  // fold BN1/BN2 + W3; pooled dot; output
  k_prep2<<<1, 256, 0, stream>>>(stats1, stats2, g1, be1, g2, be2, W3, b3, w1f, w2f, constS, (float)N);
  k_dot<<<1024, 256, 0, stream>>>(h1, h2, w1f, w2f, s, N);
  k_out<<<(B * 64 + 255) / 256, 256, 0, stream>>>(s, gofs, constS, (float*)d_out, B);
}